// Round 10
// baseline (123.410 us; speedup 1.0000x reference)
//
#include <hip/hip_runtime.h>
#include <math.h>

#define BSZ   16
#define LSEQ  1024
#define TGT   256
#define HID   512
#define TV    2000
#define VOC   3000
#define SRC   2048
#define NKE   1280     // WkE rows: 2 j-halves x 640 (512 d + sentinel + bias + pad)
#define JOFF  640
#define SCALE 0.044194173824159216f   // 1/sqrt(512)

typedef unsigned short u16;
typedef __attribute__((ext_vector_type(8))) short bf16x8;
typedef __attribute__((ext_vector_type(4))) float f32x4;

__device__ __forceinline__ u16 f2bf(float x) {
    unsigned u = __float_as_uint(x);
    u += 0x7FFFu + ((u >> 16) & 1u);
    return (u16)(u >> 16);
}
__device__ __forceinline__ float bf2f(u16 x) {
    return __uint_as_float((unsigned)x << 16);
}

static __device__ __forceinline__ float gelu_exact(float x) {
    return 0.5f * x * (1.0f + erff(x * 0.70710678118654752f));
}

// async 16B global -> LDS (wave-uniform LDS base + lane*16)
__device__ __forceinline__ void gload16(const u16* g, u16* l) {
    __builtin_amdgcn_global_load_lds(
        (const __attribute__((address_space(1))) unsigned int*)g,
        (__attribute__((address_space(3))) unsigned int*)l,
        16, 0, 0);
}

// ---------------- PREP mega-kernel ----------------
// blocks: [0,4096) cast memory_raw | [4096,5120) cast feature | [5120,5376) Wq^T |
//         [5376,5696) WkE build | [5696,6720) k_logz | 6720 rowsum=0 | [6721,6737) buckets
__device__ __forceinline__ void cast8_body(const float4* __restrict__ in,
                                           int4* __restrict__ out, int i) {
    float4 x = in[2 * i], y = in[2 * i + 1];
    unsigned p0 = (unsigned)f2bf(x.x) | ((unsigned)f2bf(x.y) << 16);
    unsigned p1 = (unsigned)f2bf(x.z) | ((unsigned)f2bf(x.w) << 16);
    unsigned p2 = (unsigned)f2bf(y.x) | ((unsigned)f2bf(y.y) << 16);
    unsigned p3 = (unsigned)f2bf(y.z) | ((unsigned)f2bf(y.w) << 16);
    out[i] = make_int4(p0, p1, p2, p3);
}

__global__ __launch_bounds__(256) void prep(
    const float* __restrict__ memory_raw, const float* __restrict__ feature,
    const float* __restrict__ Wq, const float* __restrict__ Wk,
    const float* __restrict__ sentinel, const float* __restrict__ bk,
    const float* __restrict__ logits, const int* __restrict__ ce,
    int4* __restrict__ memb, int4* __restrict__ featb,
    u16* __restrict__ wqT, u16* __restrict__ wkE,
    float* __restrict__ logZo, float* __restrict__ rowsum,
    int* __restrict__ boff, u16* __restrict__ bucket)
{
    __shared__ float t[32][33];
    __shared__ int cnt[VOC];
    __shared__ int part[256];
    const int id = blockIdx.x;
    const int tid = threadIdx.x;
    if (id < 4096) {
        cast8_body((const float4*)memory_raw, memb, id * 256 + tid);
    } else if (id < 5120) {
        cast8_body((const float4*)feature, featb, (id - 4096) * 256 + tid);
    } else if (id < 5376) {
        // Wq^T (512x512)
        int id2 = id - 5120;
        int bx = (id2 & 15) * 32, by = (id2 >> 4) * 32;
        const int tx = tid & 31, ty = tid >> 5;
        #pragma unroll
        for (int k = 0; k < 4; ++k)
            t[ty + 8 * k][tx] = Wq[(size_t)(by + ty + 8 * k) * 512 + bx + tx];
        __syncthreads();
        #pragma unroll
        for (int k = 0; k < 4; ++k)
            wqT[(size_t)(bx + ty + 8 * k) * 512 + by + tx] = f2bf(t[tx][ty + 8 * k]);
    } else if (id < 5696) {
        // WkE build: 4 rows per block, 64 threads x 8 cols per row
        const int rr = (id - 5376) * 4 + (tid >> 6);   // 0..1279
        const int c = (tid & 63) * 8;
        const int j = rr >= JOFF;
        const int dd = rr - j * JOFF;
        u16* dst = wkE + (size_t)rr * HID + c;
        if (dd < 512) {
            const float* src = Wk + (size_t)dd * 1024 + j * 512 + c;
            #pragma unroll
            for (int k = 0; k < 8; ++k) dst[k] = f2bf(src[k]);
        } else if (dd == 512) {
            #pragma unroll
            for (int k = 0; k < 8; ++k) dst[k] = f2bf(sentinel[c + k]);
        } else if (dd == 513) {
            #pragma unroll
            for (int k = 0; k < 8; ++k) dst[k] = f2bf(bk[j * 512 + c + k]);
        } else {
            #pragma unroll
            for (int k = 0; k < 8; ++k) dst[k] = 0;
        }
    } else if (id < 6720) {
        // k_logz: 4 rows per block, one wave per row (TV = 500 float4)
        const int row = (id - 5696) * 4 + (tid >> 6);
        const int lane = tid & 63;
        const float4* lrow4 = (const float4*)(logits + (size_t)row * TV);
        float4 v4[8];
        float m = -INFINITY;
        #pragma unroll
        for (int i = 0; i < 8; ++i) {
            int idx = lane + 64 * i;
            if (idx < 500) {
                v4[i] = lrow4[idx];
                m = fmaxf(m, fmaxf(fmaxf(v4[i].x, v4[i].y), fmaxf(v4[i].z, v4[i].w)));
            } else {
                v4[i] = make_float4(-INFINITY, -INFINITY, -INFINITY, -INFINITY);
            }
        }
        #pragma unroll
        for (int o = 32; o > 0; o >>= 1) m = fmaxf(m, __shfl_xor(m, o, 64));
        float s = 0.f;
        #pragma unroll
        for (int i = 0; i < 8; ++i) {
            s += __expf(v4[i].x - m) + __expf(v4[i].y - m)
               + __expf(v4[i].z - m) + __expf(v4[i].w - m);
        }
        #pragma unroll
        for (int o = 32; o > 0; o >>= 1) s += __shfl_xor(s, o, 64);
        if (lane == 0) logZo[row] = m + __logf(s);
    } else if (id == 6720) {
        // zero rowsum (4096 f32 = 1024 float4) — fresh every launch
        float4* rz = (float4*)rowsum;
        for (int i = tid; i < 1024; i += 256) rz[i] = make_float4(0.f, 0.f, 0.f, 0.f);
    } else {
        // bucket build: one block per batch. buckets of jl-indices grouped by vocab id.
        const int b = id - 6721;
        const int* ceb = ce + (size_t)b * SRC;
        for (int v = tid; v < VOC; v += 256) cnt[v] = 0;
        __syncthreads();
        for (int s = tid; s < SRC; s += 256) atomicAdd(&cnt[ceb[s]], 1);
        __syncthreads();
        // block exclusive scan over cnt[3000] (each thread 12 bins)
        const int base = tid * 12;
        int lc[12];
        int tot = 0;
        #pragma unroll
        for (int k = 0; k < 12; ++k) {
            int v = base + k;
            lc[k] = (v < VOC) ? cnt[v] : 0;
            tot += lc[k];
        }
        part[tid] = tot;
        __syncthreads();
        for (int d = 1; d < 256; d <<= 1) {
            int val = (tid >= d) ? part[tid - d] : 0;
            __syncthreads();
            part[tid] += val;
            __syncthreads();
        }
        int run = part[tid] - tot;   // exclusive prefix
        int* boffb = boff + b * 3008;
        #pragma unroll
        for (int k = 0; k < 12; ++k) {
            int v = base + k;
            if (v < VOC) { boffb[v] = run; cnt[v] = run; run += lc[k]; }
        }
        if (tid == 0) boffb[VOC] = SRC;
        __syncthreads();
        for (int s = tid; s < SRC; s += 256) {
            int idv = ceb[s];
            int jl = (s & 1) * 1024 + (s >> 1);
            int pos = atomicAdd(&cnt[idv], 1);
            bucket[(size_t)b * SRC + pos] = (u16)jl;
        }
    }
}

// ---------------- MFMA GEMM body: C = A[M,512] . B^T[N,512], 128x128 tile ----------------
// EPI 1: query (+bq, gelu) -> bf16 [m][512]
// EPI 3: qk (plain)        -> bf16 [m][1280]
// EPI 2: atten TRANSPOSED: A=mem rows l, B=qk rows t. out E_T[b][jl][t] = exp bf16;
//        per-col sums atomically into rowsum. z=(b,jj)
template<int EPI, int LDA, int LDB>
__device__ __forceinline__ void gemm_body(
    int m0, int n0, int z,
    const u16* __restrict__ Abase, const u16* __restrict__ Bbase,
    const float* __restrict__ bias, u16* __restrict__ outb,
    const int* __restrict__ ce, float* __restrict__ rowsum,
    u16* __restrict__ As, u16* __restrict__ Bs)   // each 2*4096 u16
{
    const int tid = threadIdx.x;
    const int lane = tid & 63;
    const int w = tid >> 6;
    const int wr = (w >> 1) * 64, wc = (w & 1) * 64;

    const u16* Ag = Abase;
    const u16* Bg = Bbase;
    if (EPI == 2) {
        Ag = Abase + (size_t)(z >> 1) * LSEQ * HID;                       // memb[b]
        Bg = Bbase + (size_t)(z >> 1) * TGT * NKE + (size_t)(z & 1) * JOFF; // qk[b], jj half
    }

    const int chunkrow = lane >> 2;
    const int colc = (lane & 3) * 8;
    const int c0 = w * 2, c1 = c0 + 1;
    const u16* gA0 = Ag + (size_t)(m0 + c0 * 16 + chunkrow) * LDA + colc;
    const u16* gA1 = Ag + (size_t)(m0 + c1 * 16 + chunkrow) * LDA + colc;
    const u16* gB0 = Bg + (size_t)(n0 + c0 * 16 + chunkrow) * LDB + colc;
    const u16* gB1 = Bg + (size_t)(n0 + c1 * 16 + chunkrow) * LDB + colc;

    const int la = lane & 15, lb = lane >> 4;
    f32x4 acc[4][4] = {};

    gload16(gA0, As + c0 * 512);
    gload16(gA1, As + c1 * 512);
    gload16(gB0, Bs + c0 * 512);
    gload16(gB1, Bs + c1 * 512);

    int cur = 0;
    for (int k0 = 0; k0 < HID; k0 += 32) {
        __syncthreads();   // drains vmcnt(0) (stage complete) + barrier
        const u16* Asb = As + cur * 4096;
        const u16* Bsb = Bs + cur * 4096;
        bf16x8 af[4], bfv[4];
        #pragma unroll
        for (int i = 0; i < 4; ++i)
            af[i] = *(const bf16x8*)(Asb + (wr + i * 16 + la) * 32 + lb * 8);
        #pragma unroll
        for (int j = 0; j < 4; ++j)
            bfv[j] = *(const bf16x8*)(Bsb + (wc + j * 16 + la) * 32 + lb * 8);
        if (k0 + 32 < HID) {
            const int nb = cur ^ 1;
            u16* An = As + nb * 4096;
            u16* Bn = Bs + nb * 4096;
            gload16(gA0 + k0 + 32, An + c0 * 512);
            gload16(gA1 + k0 + 32, An + c1 * 512);
            gload16(gB0 + k0 + 32, Bn + c0 * 512);
            gload16(gB1 + k0 + 32, Bn + c1 * 512);
        }
        #pragma unroll
        for (int i = 0; i < 4; ++i)
            #pragma unroll
            for (int j = 0; j < 4; ++j)
                acc[i][j] = __builtin_amdgcn_mfma_f32_16x16x32_bf16(af[i], bfv[j], acc[i][j], 0, 0, 0);
        cur ^= 1;
    }

    const int r_l = (lane >> 4) * 4, c_l = lane & 15;
    if (EPI == 1) {
        #pragma unroll
        for (int j = 0; j < 4; ++j) {
            const int n = n0 + wc + j * 16 + c_l;
            const float bv = bias[n];
            #pragma unroll
            for (int i = 0; i < 4; ++i)
                #pragma unroll
                for (int r = 0; r < 4; ++r) {
                    const int m = m0 + wr + i * 16 + r_l + r;
                    outb[(size_t)m * HID + n] = f2bf(gelu_exact(acc[i][j][r] + bv));
                }
        }
    } else if (EPI == 3) {
        #pragma unroll
        for (int j = 0; j < 4; ++j) {
            const int n = n0 + wc + j * 16 + c_l;
            #pragma unroll
            for (int i = 0; i < 4; ++i)
                #pragma unroll
                for (int r = 0; r < 4; ++r) {
                    const int m = m0 + wr + i * 16 + r_l + r;
                    outb[(size_t)m * NKE + n] = f2bf(acc[i][j][r]);
                }
        }
    } else {
        const int b = z >> 1, jj = z & 1;
        // per-col (t) bias = q.bk_j gathered from qk; per-row (l) mask from raw ce
        float biasc[4];
        #pragma unroll
        for (int j = 0; j < 4; ++j) {
            const int n = n0 + wc + j * 16 + c_l;   // t
            biasc[j] = bf2f(Bbase[(size_t)(b * TGT + n) * NKE + jj * JOFF + 513]);
        }
        const int* ceb = ce + (size_t)b * SRC;
        float csum[4] = {0.f, 0.f, 0.f, 0.f};
        #pragma unroll
        for (int i = 0; i < 4; ++i)
            #pragma unroll
            for (int r = 0; r < 4; ++r) {
                const int m = m0 + wr + i * 16 + r_l + r;      // l
                const int cm = ceb[2 * m + jj];
                const size_t rowbase = ((size_t)b * SRC + jj * 1024 + m) * TGT;
                #pragma unroll
                for (int j = 0; j < 4; ++j) {
                    float ev = (cm == 0) ? 0.f
                             : __expf((acc[i][j][r] + biasc[j]) * SCALE);
                    outb[rowbase + n0 + wc + j * 16 + c_l] = f2bf(ev);
                    csum[j] += ev;
                }
            }
        #pragma unroll
        for (int j = 0; j < 4; ++j) {
            csum[j] += __shfl_xor(csum[j], 16, 64);
            csum[j] += __shfl_xor(csum[j], 32, 64);
        }
        const int jsel = lane >> 4;
        float myv = (jsel == 0) ? csum[0] : (jsel == 1) ? csum[1]
                  : (jsel == 2) ? csum[2] : csum[3];
        atomicAdd(&rowsum[b * TGT + n0 + wc + jsel * 16 + c_l], myv);
    }
}

__global__ __launch_bounds__(256) void gemm_query(
    const u16* __restrict__ feat, const u16* __restrict__ wqT,
    const float* __restrict__ bq, u16* __restrict__ queryb)
{
    __shared__ u16 As[2 * 4096];
    __shared__ u16 Bs[2 * 4096];
    gemm_body<1, 512, 512>(blockIdx.y * 128, blockIdx.x * 128, 0,
                           feat, wqT, bq, queryb, nullptr, nullptr, As, Bs);
}

__global__ __launch_bounds__(256) void gemm_qk(
    const u16* __restrict__ queryb, const u16* __restrict__ wkE,
    u16* __restrict__ qkb)
{
    __shared__ u16 As[2 * 4096];
    __shared__ u16 Bs[2 * 4096];
    gemm_body<3, 512, 512>(blockIdx.y * 128, blockIdx.x * 128, 0,
                           queryb, wkE, nullptr, qkb, nullptr, nullptr, As, Bs);
}

__global__ __launch_bounds__(256) void gemm_atten(
    const u16* __restrict__ memb, const u16* __restrict__ qkb,
    const int* __restrict__ ce, float* __restrict__ rowsum,
    u16* __restrict__ etb)
{
    __shared__ u16 As[2 * 4096];
    __shared__ u16 Bs[2 * 4096];
    gemm_body<2, 512, NKE>(blockIdx.y * 128, blockIdx.x * 128, blockIdx.z,
                           memb, qkb, nullptr, etb, ce, rowsum, As, Bs);
}

// ---------------- combine: bucket-gather segment-sum + final logsumexp, no atomics ----------------
// grid (94 v-chunks, 16 batches). Each block: 32 v x all 256 t.
__global__ __launch_bounds__(256) void combine(
    const u16* __restrict__ etb, const u16* __restrict__ bucket,
    const int* __restrict__ boff, const u16* __restrict__ qkb,
    const float* __restrict__ rowsum, const float* __restrict__ logZo,
    const float* __restrict__ out_logits, float* __restrict__ out)
{
    __shared__ float accS[32][257];
    __shared__ float rcInv[TGT], rcGZ[TGT], rcEdl[TGT], rcDl[TGT];
    const int b = blockIdx.y;
    const int v0 = blockIdx.x * 32;
    const int tid = threadIdx.x;
    const float EPSF = 1.1920929e-07f;

    // per-t row constants (thread t)
    {
        const int bt = b * TGT + tid;
        float sent_v = bf2f(qkb[(size_t)bt * NKE + 512]) * SCALE;
        float se = __expf(sent_v);
        float sm = rowsum[bt] + se;
        float inv = 1.0f / sm;
        float g = sent_v - __logf(sm);
        float eg = se * inv;
        float dl = __logf(1.0f - eg + EPSF) - log1pf(-eg + EPSF);
        rcInv[tid] = inv;
        rcGZ[tid] = g - logZo[bt];
        rcEdl[tid] = __expf(dl);
        rcDl[tid] = dl;
    }

    // bucket gather: wave w owns v-locals [w*8, w*8+8); lane holds 4 t values
    const int w = tid >> 6, lane = tid & 63;
    const int* boffb = boff + b * 3008;
    #pragma unroll
    for (int vl8 = 0; vl8 < 8; ++vl8) {
        const int vloc = w * 8 + vl8;
        const int v = v0 + vloc;
        float a0 = 0.f, a1 = 0.f, a2 = 0.f, a3 = 0.f;
        if (v < VOC) {
            const int e0 = boffb[v], e1 = boffb[v + 1];
            for (int e = e0; e < e1; ++e) {
                const int s = bucket[(size_t)b * SRC + e];
                ushort4 u = *(const ushort4*)(etb + ((size_t)b * SRC + s) * TGT + lane * 4);
                a0 += bf2f(u.x); a1 += bf2f(u.y); a2 += bf2f(u.z); a3 += bf2f(u.w);
            }
        }
        accS[vloc][lane * 4 + 0] = a0;
        accS[vloc][lane * 4 + 1] = a1;
        accS[vloc][lane * 4 + 2] = a2;
        accS[vloc][lane * 4 + 3] = a3;
    }
    __syncthreads();

    // combine: thread = (tloc, vloc); iterate 32 t-groups of 8
    const int tloc = tid >> 5, vloc = tid & 31;
    const int v = v0 + vloc;
    if (v < VOC) {
        const bool hasl = (v < TV);
        for (int g8 = 0; g8 < 32; ++g8) {
            const int t = g8 * 8 + tloc;
            const int bt = b * TGT + t;
            float pv = accS[vloc][t] * rcInv[t] + EPSF;
            float o;
            if (hasl) {
                float lv = out_logits[(size_t)bt * TV + v];
                o = __logf(__expf(lv + rcGZ[t]) + pv * rcEdl[t]);
            } else {
                o = __logf(pv) + rcDl[t];
            }
            out[(size_t)bt * VOC + v] = o;
        }
    }
}

extern "C" void kernel_launch(void* const* d_in, const int* in_sizes, int n_in,
                              void* d_out, int out_size, void* d_ws, size_t ws_size,
                              hipStream_t stream) {
    const float* out_logits = (const float*)d_in[0];
    const float* feature    = (const float*)d_in[1];
    const float* memory_raw = (const float*)d_in[2];
    const int*   content_e  = (const int*)d_in[3];
    const float* Wq = (const float*)d_in[4];
    const float* bq = (const float*)d_in[5];
    const float* Wk = (const float*)d_in[6];
    const float* bk = (const float*)d_in[7];
    const float* sentinel = (const float*)d_in[8];
    float* out = (float*)d_out;

    u16* memb   = (u16*)d_ws;                             // 16384*512 bf16
    u16* featb  = memb   + (size_t)16384 * 512;           // 4096*512
    u16* wqT    = featb  + (size_t)4096 * 512;            // 512*512
    u16* wkE    = wqT    + (size_t)512 * 512;             // 1280*512
    u16* queryb = wkE    + (size_t)NKE * 512;             // 4096*512
    u16* qkb    = queryb + (size_t)4096 * 512;            // 4096*1280
    u16* etb    = qkb    + (size_t)4096 * NKE;            // 16*2048*256 bf16 E^T
    float* logZo = (float*)(etb + (size_t)BSZ * SRC * TGT); // 4096 f32
    float* rowsum = logZo + 4096;                         // 4096 f32
    int* boff = (int*)(rowsum + 4096);                    // 16*3008 int
    u16* bucket = (u16*)(boff + 16 * 3008);               // 16*2048 u16

    prep<<<6737, 256, 0, stream>>>(memory_raw, feature, Wq, Wk, sentinel, bk,
                                   out_logits, content_e,
                                   (int4*)memb, (int4*)featb, wqT, wkE, logZo,
                                   rowsum, boff, bucket);
    gemm_query<<<dim3(4, 32), 256, 0, stream>>>(featb, wqT, bq, queryb);
    gemm_qk<<<dim3(10, 32), 256, 0, stream>>>(queryb, wkE, qkb);
    gemm_atten<<<dim3(TGT / 128, LSEQ / 128, 32), 256, 0, stream>>>(
        memb, qkb, content_e, rowsum, etb);
    combine<<<dim3(94, BSZ), 256, 0, stream>>>(etb, bucket, boff, qkb,
                                               rowsum, logZo, out_logits, out);
}

// Round 12
// 112.373 us; speedup vs baseline: 1.0982x; 1.0982x over previous
//
#include <hip/hip_runtime.h>
#include <math.h>

#define BSZ   16
#define LSEQ  1024
#define TGT   256
#define HID   512
#define TV    2000
#define VOC   3000
#define SRC   2048
#define NKE   1280     // WkE rows: 2 j-halves x 640 (512 d + sentinel + bias + pad)
#define JOFF  640
#define SCALE 0.044194173824159216f   // 1/sqrt(512)

typedef unsigned short u16;
typedef __attribute__((ext_vector_type(8))) short bf16x8;
typedef __attribute__((ext_vector_type(4))) float f32x4;

__device__ __forceinline__ u16 f2bf(float x) {
    unsigned u = __float_as_uint(x);
    u += 0x7FFFu + ((u >> 16) & 1u);
    return (u16)(u >> 16);
}
__device__ __forceinline__ float bf2f(u16 x) {
    return __uint_as_float((unsigned)x << 16);
}

static __device__ __forceinline__ float gelu_exact(float x) {
    return 0.5f * x * (1.0f + erff(x * 0.70710678118654752f));
}

// async 16B global -> LDS (wave-uniform LDS base + lane*16)
__device__ __forceinline__ void gload16(const u16* g, u16* l) {
    __builtin_amdgcn_global_load_lds(
        (const __attribute__((address_space(1))) unsigned int*)g,
        (__attribute__((address_space(3))) unsigned int*)l,
        16, 0, 0);
}

// ---------------- PREP mega-kernel ----------------
// blocks: [0,4096) cast memory_raw | [4096,5120) cast feature | [5120,5376) Wq^T |
//         [5376,5696) WkE build | 5696 rowsum=0 | [5697,5713) buckets
__device__ __forceinline__ void cast8_body(const float4* __restrict__ in,
                                           int4* __restrict__ out, int i) {
    float4 x = in[2 * i], y = in[2 * i + 1];
    unsigned p0 = (unsigned)f2bf(x.x) | ((unsigned)f2bf(x.y) << 16);
    unsigned p1 = (unsigned)f2bf(x.z) | ((unsigned)f2bf(x.w) << 16);
    unsigned p2 = (unsigned)f2bf(y.x) | ((unsigned)f2bf(y.y) << 16);
    unsigned p3 = (unsigned)f2bf(y.z) | ((unsigned)f2bf(y.w) << 16);
    out[i] = make_int4(p0, p1, p2, p3);
}

__global__ __launch_bounds__(256) void prep(
    const float* __restrict__ memory_raw, const float* __restrict__ feature,
    const float* __restrict__ Wq, const float* __restrict__ Wk,
    const float* __restrict__ sentinel, const float* __restrict__ bk,
    const int* __restrict__ ce,
    int4* __restrict__ memb, int4* __restrict__ featb,
    u16* __restrict__ wqT, u16* __restrict__ wkE,
    float* __restrict__ rowsum,
    int* __restrict__ boff, u16* __restrict__ bucket)
{
    __shared__ float t[32][33];
    __shared__ int cnt[VOC];
    __shared__ int part[256];
    const int id = blockIdx.x;
    const int tid = threadIdx.x;
    if (id < 4096) {
        cast8_body((const float4*)memory_raw, memb, id * 256 + tid);
    } else if (id < 5120) {
        cast8_body((const float4*)feature, featb, (id - 4096) * 256 + tid);
    } else if (id < 5376) {
        // Wq^T (512x512)
        int id2 = id - 5120;
        int bx = (id2 & 15) * 32, by = (id2 >> 4) * 32;
        const int tx = tid & 31, ty = tid >> 5;
        #pragma unroll
        for (int k = 0; k < 4; ++k)
            t[ty + 8 * k][tx] = Wq[(size_t)(by + ty + 8 * k) * 512 + bx + tx];
        __syncthreads();
        #pragma unroll
        for (int k = 0; k < 4; ++k)
            wqT[(size_t)(bx + ty + 8 * k) * 512 + by + tx] = f2bf(t[tx][ty + 8 * k]);
    } else if (id < 5696) {
        // WkE build: 4 rows per block, 64 threads x 8 cols per row
        const int rr = (id - 5376) * 4 + (tid >> 6);   // 0..1279
        const int c = (tid & 63) * 8;
        const int j = rr >= JOFF;
        const int dd = rr - j * JOFF;
        u16* dst = wkE + (size_t)rr * HID + c;
        if (dd < 512) {
            const float* src = Wk + (size_t)dd * 1024 + j * 512 + c;
            #pragma unroll
            for (int k = 0; k < 8; ++k) dst[k] = f2bf(src[k]);
        } else if (dd == 512) {
            #pragma unroll
            for (int k = 0; k < 8; ++k) dst[k] = f2bf(sentinel[c + k]);
        } else if (dd == 513) {
            #pragma unroll
            for (int k = 0; k < 8; ++k) dst[k] = f2bf(bk[j * 512 + c + k]);
        } else {
            #pragma unroll
            for (int k = 0; k < 8; ++k) dst[k] = 0;
        }
    } else if (id == 5696) {
        // zero rowsum (4096 f32 = 1024 float4) — fresh every launch
        float4* rz = (float4*)rowsum;
        for (int i = tid; i < 1024; i += 256) rz[i] = make_float4(0.f, 0.f, 0.f, 0.f);
    } else {
        // bucket build: one block per batch. buckets of jl-indices grouped by vocab id.
        const int b = id - 5697;
        const int* ceb = ce + (size_t)b * SRC;
        for (int v = tid; v < VOC; v += 256) cnt[v] = 0;
        __syncthreads();
        for (int s = tid; s < SRC; s += 256) atomicAdd(&cnt[ceb[s]], 1);
        __syncthreads();
        // block exclusive scan over cnt[3000] (each thread 12 bins)
        const int base = tid * 12;
        int lc[12];
        int tot = 0;
        #pragma unroll
        for (int k = 0; k < 12; ++k) {
            int v = base + k;
            lc[k] = (v < VOC) ? cnt[v] : 0;
            tot += lc[k];
        }
        part[tid] = tot;
        __syncthreads();
        for (int d = 1; d < 256; d <<= 1) {
            int val = (tid >= d) ? part[tid - d] : 0;
            __syncthreads();
            part[tid] += val;
            __syncthreads();
        }
        int run = part[tid] - tot;   // exclusive prefix
        int* boffb = boff + b * 3008;
        #pragma unroll
        for (int k = 0; k < 12; ++k) {
            int v = base + k;
            if (v < VOC) { boffb[v] = run; cnt[v] = run; run += lc[k]; }
        }
        if (tid == 0) boffb[VOC] = SRC;
        __syncthreads();
        for (int s = tid; s < SRC; s += 256) {
            int idv = ceb[s];
            int jl = (s & 1) * 1024 + (s >> 1);
            int pos = atomicAdd(&cnt[idv], 1);
            bucket[(size_t)b * SRC + pos] = (u16)jl;
        }
    }
}

// ---------------- query GEMM: 64x64 tile, BK=32 (512 blocks for TLP) ----------------
__global__ __launch_bounds__(256) void gemm_query(
    const u16* __restrict__ feat, const u16* __restrict__ wqT,
    const float* __restrict__ bq, u16* __restrict__ queryb)
{
    __shared__ u16 As[2 * 2048];
    __shared__ u16 Bs[2 * 2048];
    const int tid = threadIdx.x;
    const int lane = tid & 63;
    const int w = tid >> 6;
    const int wr = (w >> 1) * 32, wc = (w & 1) * 32;
    const int m0 = blockIdx.y * 64, n0 = blockIdx.x * 64;

    const int srow = tid >> 2, scol = (tid & 3) * 8;
    const u16* gA = feat + (size_t)(m0 + srow) * HID + scol;
    const u16* gB = wqT + (size_t)(n0 + srow) * HID + scol;

    const int la = lane & 15, lb = lane >> 4;
    f32x4 acc[2][2] = {};

    gload16(gA, As + w * 512);
    gload16(gB, Bs + w * 512);

    int cur = 0;
    for (int k0 = 0; k0 < HID; k0 += 32) {
        __syncthreads();   // drains vmcnt(0) + barrier
        const u16* Asb = As + cur * 2048;
        const u16* Bsb = Bs + cur * 2048;
        bf16x8 af[2], bf[2];
        #pragma unroll
        for (int i = 0; i < 2; ++i)
            af[i] = *(const bf16x8*)(Asb + (wr + i * 16 + la) * 32 + lb * 8);
        #pragma unroll
        for (int j = 0; j < 2; ++j)
            bf[j] = *(const bf16x8*)(Bsb + (wc + j * 16 + la) * 32 + lb * 8);
        if (k0 + 32 < HID) {
            const int nb = cur ^ 1;
            gload16(gA + k0 + 32, As + nb * 2048 + w * 512);
            gload16(gB + k0 + 32, Bs + nb * 2048 + w * 512);
        }
        #pragma unroll
        for (int i = 0; i < 2; ++i)
            #pragma unroll
            for (int j = 0; j < 2; ++j)
                acc[i][j] = __builtin_amdgcn_mfma_f32_16x16x32_bf16(af[i], bf[j], acc[i][j], 0, 0, 0);
        cur ^= 1;
    }

    const int r_l = (lane >> 4) * 4, c_l = lane & 15;
    #pragma unroll
    for (int j = 0; j < 2; ++j) {
        const int n = n0 + wc + j * 16 + c_l;
        const float bv = bq[n];
        #pragma unroll
        for (int i = 0; i < 2; ++i)
            #pragma unroll
            for (int r = 0; r < 4; ++r) {
                const int m = m0 + wr + i * 16 + r_l + r;
                queryb[(size_t)m * HID + n] = f2bf(gelu_exact(acc[i][j][r] + bv));
            }
    }
}

// ---------------- MFMA GEMM body (128x128, BK=32) for qk and atten ----------------
// EPI 3: qk (plain)  -> bf16 [m][1280]
// EPI 2: atten TRANSPOSED: A=mem rows l, B=qk rows t. out E_T[b][jl][t]=exp bf16;
//        per-col sums atomically into rowsum. z=(b,jj)
template<int EPI, int LDA, int LDB>
__device__ __forceinline__ void gemm_body(
    int m0, int n0, int z,
    const u16* __restrict__ Abase, const u16* __restrict__ Bbase,
    u16* __restrict__ outb,
    const int* __restrict__ ce, float* __restrict__ rowsum,
    u16* __restrict__ As, u16* __restrict__ Bs)   // each 2*4096 u16
{
    const int tid = threadIdx.x;
    const int lane = tid & 63;
    const int w = tid >> 6;
    const int wr = (w >> 1) * 64, wc = (w & 1) * 64;

    const u16* Ag = Abase;
    const u16* Bg = Bbase;
    if (EPI == 2) {
        Ag = Abase + (size_t)(z >> 1) * LSEQ * HID;                        // memb[b]
        Bg = Bbase + (size_t)(z >> 1) * TGT * NKE + (size_t)(z & 1) * JOFF; // qk[b], jj half
    }

    const int chunkrow = lane >> 2;
    const int colc = (lane & 3) * 8;
    const int c0 = w * 2, c1 = c0 + 1;
    const u16* gA0 = Ag + (size_t)(m0 + c0 * 16 + chunkrow) * LDA + colc;
    const u16* gA1 = Ag + (size_t)(m0 + c1 * 16 + chunkrow) * LDA + colc;
    const u16* gB0 = Bg + (size_t)(n0 + c0 * 16 + chunkrow) * LDB + colc;
    const u16* gB1 = Bg + (size_t)(n0 + c1 * 16 + chunkrow) * LDB + colc;

    const int la = lane & 15, lb = lane >> 4;
    f32x4 acc[4][4] = {};

    gload16(gA0, As + c0 * 512);
    gload16(gA1, As + c1 * 512);
    gload16(gB0, Bs + c0 * 512);
    gload16(gB1, Bs + c1 * 512);

    int cur = 0;
    for (int k0 = 0; k0 < HID; k0 += 32) {
        __syncthreads();   // drains vmcnt(0) (stage complete) + barrier
        const u16* Asb = As + cur * 4096;
        const u16* Bsb = Bs + cur * 4096;
        bf16x8 af[4], bfv[4];
        #pragma unroll
        for (int i = 0; i < 4; ++i)
            af[i] = *(const bf16x8*)(Asb + (wr + i * 16 + la) * 32 + lb * 8);
        #pragma unroll
        for (int j = 0; j < 4; ++j)
            bfv[j] = *(const bf16x8*)(Bsb + (wc + j * 16 + la) * 32 + lb * 8);
        if (k0 + 32 < HID) {
            const int nb = cur ^ 1;
            u16* An = As + nb * 4096;
            u16* Bn = Bs + nb * 4096;
            gload16(gA0 + k0 + 32, An + c0 * 512);
            gload16(gA1 + k0 + 32, An + c1 * 512);
            gload16(gB0 + k0 + 32, Bn + c0 * 512);
            gload16(gB1 + k0 + 32, Bn + c1 * 512);
        }
        #pragma unroll
        for (int i = 0; i < 4; ++i)
            #pragma unroll
            for (int j = 0; j < 4; ++j)
                acc[i][j] = __builtin_amdgcn_mfma_f32_16x16x32_bf16(af[i], bfv[j], acc[i][j], 0, 0, 0);
        cur ^= 1;
    }

    const int r_l = (lane >> 4) * 4, c_l = lane & 15;
    if (EPI == 3) {
        #pragma unroll
        for (int j = 0; j < 4; ++j) {
            const int n = n0 + wc + j * 16 + c_l;
            #pragma unroll
            for (int i = 0; i < 4; ++i)
                #pragma unroll
                for (int r = 0; r < 4; ++r) {
                    const int m = m0 + wr + i * 16 + r_l + r;
                    outb[(size_t)m * NKE + n] = f2bf(acc[i][j][r]);
                }
        }
    } else {
        const int b = z >> 1, jj = z & 1;
        // per-col (t) bias = q.bk_j gathered from qk; per-row (l) mask from raw ce
        float biasc[4];
        #pragma unroll
        for (int j = 0; j < 4; ++j) {
            const int n = n0 + wc + j * 16 + c_l;   // t
            biasc[j] = bf2f(Bbase[(size_t)(b * TGT + n) * NKE + jj * JOFF + 513]);
        }
        const int* ceb = ce + (size_t)b * SRC;
        float csum[4] = {0.f, 0.f, 0.f, 0.f};
        #pragma unroll
        for (int i = 0; i < 4; ++i)
            #pragma unroll
            for (int r = 0; r < 4; ++r) {
                const int m = m0 + wr + i * 16 + r_l + r;      // l
                const int cm = ceb[2 * m + jj];
                const size_t rowbase = ((size_t)b * SRC + jj * 1024 + m) * TGT;
                #pragma unroll
                for (int j = 0; j < 4; ++j) {
                    float ev = (cm == 0) ? 0.f
                             : __expf((acc[i][j][r] + biasc[j]) * SCALE);
                    outb[rowbase + n0 + wc + j * 16 + c_l] = f2bf(ev);
                    csum[j] += ev;
                }
            }
        #pragma unroll
        for (int j = 0; j < 4; ++j) {
            csum[j] += __shfl_xor(csum[j], 16, 64);
            csum[j] += __shfl_xor(csum[j], 32, 64);
        }
        const int jsel = lane >> 4;
        float myv = (jsel == 0) ? csum[0] : (jsel == 1) ? csum[1]
                  : (jsel == 2) ? csum[2] : csum[3];
        atomicAdd(&rowsum[b * TGT + n0 + wc + jsel * 16 + c_l], myv);
    }
}

__global__ __launch_bounds__(256) void gemm_qk(
    const u16* __restrict__ queryb, const u16* __restrict__ wkE,
    u16* __restrict__ qkb)
{
    __shared__ u16 As[2 * 4096];
    __shared__ u16 Bs[2 * 4096];
    gemm_body<3, 512, 512>(blockIdx.y * 128, blockIdx.x * 128, 0,
                           queryb, wkE, qkb, nullptr, nullptr, As, Bs);
}

// atten: 512 blocks = 32 (b,jj) x 16 inner tiles, XCD-grouped:
// all 16 inner tiles of a (b,jj) share i&7 -> one XCD's L2.
__global__ __launch_bounds__(256) void gemm_atten(
    const u16* __restrict__ memb, const u16* __restrict__ qkb,
    const int* __restrict__ ce, float* __restrict__ rowsum,
    u16* __restrict__ etb)
{
    __shared__ u16 As[2 * 4096];
    __shared__ u16 Bs[2 * 4096];
    const int i = blockIdx.x;
    const int xcd = i & 7, slot = i >> 3;        // slot in [0,64)
    const int bjj = xcd + 8 * (slot >> 4);       // [0,32) = b*2+jj
    const int inner = slot & 15;                 // 8 l-tiles x 2 t-tiles
    gemm_body<2, 512, NKE>((inner >> 1) * 128, (inner & 1) * 128, bjj,
                           memb, qkb, etb, ce, rowsum, As, Bs);
}

// ---------------- combine-v2: per (b, 8-t-chunk), fused LSE + bucket gather + output ----------------
// 512 blocks, XCD-grouped per batch. No global logZ pass; logits read here (L2-hot on re-read).
__global__ __launch_bounds__(256) void combine(
    const u16* __restrict__ etb, const u16* __restrict__ bucket,
    const int* __restrict__ boff, const u16* __restrict__ qkb,
    const float* __restrict__ rowsum,
    const float* __restrict__ out_logits, float* __restrict__ out)
{
    __shared__ float acc[256][9];   // [v-local][t-local(8) + pad]
    __shared__ float rcInv[8], rcGZ[8], rcEdl[8], rcDl[8];
    const int i = blockIdx.x;
    const int xcd = i & 7, slot = i >> 3;
    const int b = xcd + 8 * (slot >> 5);   // all 32 t-chunks of b on one XCD
    const int tc = slot & 31;
    const int t0 = tc * 8;
    const int tid = threadIdx.x;
    const int w = tid >> 6, lane = tid & 63;
    const float EPSF = 1.1920929e-07f;

    // Phase A: LSE of 8 logits rows (wave w -> rows 2w, 2w+1) + row constants
    #pragma unroll
    for (int rr = 0; rr < 2; ++rr) {
        const int r = 2 * w + rr;
        const int bt = b * TGT + t0 + r;
        const float4* lrow4 = (const float4*)(out_logits + (size_t)bt * TV);
        float4 v4[8];
        float m = -INFINITY;
        #pragma unroll
        for (int k = 0; k < 8; ++k) {
            int idx = lane + 64 * k;
            if (idx < 500) {
                v4[k] = lrow4[idx];
                m = fmaxf(m, fmaxf(fmaxf(v4[k].x, v4[k].y), fmaxf(v4[k].z, v4[k].w)));
            } else {
                v4[k] = make_float4(-INFINITY, -INFINITY, -INFINITY, -INFINITY);
            }
        }
        #pragma unroll
        for (int o = 32; o > 0; o >>= 1) m = fmaxf(m, __shfl_xor(m, o, 64));
        float s = 0.f;
        #pragma unroll
        for (int k = 0; k < 8; ++k)
            s += __expf(v4[k].x - m) + __expf(v4[k].y - m)
               + __expf(v4[k].z - m) + __expf(v4[k].w - m);
        #pragma unroll
        for (int o = 32; o > 0; o >>= 1) s += __shfl_xor(s, o, 64);
        if (lane == 0) {
            const float lse = m + __logf(s);
            const float sent_v = bf2f(qkb[(size_t)bt * NKE + 512]) * SCALE;
            const float se = __expf(sent_v);
            const float sm = rowsum[bt] + se;
            const float inv = 1.0f / sm;
            const float g = sent_v - __logf(sm);
            const float eg = se * inv;
            const float dl = __logf(1.0f - eg + EPSF) - log1pf(-eg + EPSF);
            rcInv[r] = inv;
            rcGZ[r] = g - lse;
            rcEdl[r] = __expf(dl);
            rcDl[r] = dl;
        }
    }

    // Phase B: 12 v-chunks of 256
    const int* boffb = boff + b * 3008;
    const u16* bukb = bucket + (size_t)b * SRC;
    const u16* etbb = etb + (size_t)b * SRC * TGT;
    for (int vc = 0; vc < 12; ++vc) {
        const int vbase = vc * 256;
        __syncthreads();   // prev-chunk readers done; also covers rc* visibility at vc=0
        // gather: thread owns v = vbase + tid
        {
            float a[8] = {0.f, 0.f, 0.f, 0.f, 0.f, 0.f, 0.f, 0.f};
            const int v = vbase + tid;
            if (v < VOC) {
                const int e0 = boffb[v], e1 = boffb[v + 1];
                for (int e = e0; e < e1; ++e) {
                    const int s = bukb[e];
                    int4 u = *(const int4*)(etbb + (size_t)s * TGT + t0);
                    a[0] += bf2f((u16)(u.x & 0xffff));
                    a[1] += bf2f((u16)((unsigned)u.x >> 16));
                    a[2] += bf2f((u16)(u.y & 0xffff));
                    a[3] += bf2f((u16)((unsigned)u.y >> 16));
                    a[4] += bf2f((u16)(u.z & 0xffff));
                    a[5] += bf2f((u16)((unsigned)u.z >> 16));
                    a[6] += bf2f((u16)(u.w & 0xffff));
                    a[7] += bf2f((u16)((unsigned)u.w >> 16));
                }
            }
            #pragma unroll
            for (int k = 0; k < 8; ++k) acc[tid][k] = a[k];
        }
        __syncthreads();
        // output: thread = (r = tid>>5, 8 v's at vl = (tid&31)*8)
        const int r = tid >> 5;
        const int vl = (tid & 31) * 8;
        const int v8 = vbase + vl;
        if (v8 < VOC) {   // TV(2000) and VOC(3000) both 8-aligned within 256-chunks
            const int bt = b * TGT + t0 + r;
            const float inv = rcInv[r], gZ = rcGZ[r], edl = rcEdl[r], dlv = rcDl[r];
            float o8[8];
            if (v8 < TV) {
                const float4 lv0 = *(const float4*)(out_logits + (size_t)bt * TV + v8);
                const float4 lv1 = *(const float4*)(out_logits + (size_t)bt * TV + v8 + 4);
                const float lvs[8] = {lv0.x, lv0.y, lv0.z, lv0.w, lv1.x, lv1.y, lv1.z, lv1.w};
                #pragma unroll
                for (int k = 0; k < 8; ++k) {
                    float pv = acc[vl + k][r] * inv + EPSF;
                    o8[k] = __logf(__expf(lvs[k] + gZ) + pv * edl);
                }
            } else {
                #pragma unroll
                for (int k = 0; k < 8; ++k) {
                    float pv = acc[vl + k][r] * inv + EPSF;
                    o8[k] = __logf(pv) + dlv;
                }
            }
            float* op = out + (size_t)bt * VOC + v8;
            *(float4*)op = make_float4(o8[0], o8[1], o8[2], o8[3]);
            *(float4*)(op + 4) = make_float4(o8[4], o8[5], o8[6], o8[7]);
        }
    }
}

extern "C" void kernel_launch(void* const* d_in, const int* in_sizes, int n_in,
                              void* d_out, int out_size, void* d_ws, size_t ws_size,
                              hipStream_t stream) {
    const float* out_logits = (const float*)d_in[0];
    const float* feature    = (const float*)d_in[1];
    const float* memory_raw = (const float*)d_in[2];
    const int*   content_e  = (const int*)d_in[3];
    const float* Wq = (const float*)d_in[4];
    const float* bq = (const float*)d_in[5];
    const float* Wk = (const float*)d_in[6];
    const float* bk = (const float*)d_in[7];
    const float* sentinel = (const float*)d_in[8];
    float* out = (float*)d_out;

    u16* memb   = (u16*)d_ws;                             // 16384*512 bf16
    u16* featb  = memb   + (size_t)16384 * 512;           // 4096*512
    u16* wqT    = featb  + (size_t)4096 * 512;            // 512*512
    u16* wkE    = wqT    + (size_t)512 * 512;             // 1280*512
    u16* queryb = wkE    + (size_t)NKE * 512;             // 4096*512
    u16* qkb    = queryb + (size_t)4096 * 512;            // 4096*1280
    u16* etb    = qkb    + (size_t)4096 * NKE;            // 16*2048*256 bf16 E^T
    float* rowsum = (float*)(etb + (size_t)BSZ * SRC * TGT); // 4096 f32
    int* boff = (int*)(rowsum + 4096);                    // 16*3008 int
    u16* bucket = (u16*)(boff + 16 * 3008);               // 16*2048 u16

    prep<<<5713, 256, 0, stream>>>(memory_raw, feature, Wq, Wk, sentinel, bk,
                                   content_e,
                                   (int4*)memb, (int4*)featb, wqT, wkE,
                                   rowsum, boff, bucket);
    gemm_query<<<dim3(8, 64), 256, 0, stream>>>(featb, wqT, bq, queryb);
    gemm_qk<<<dim3(10, 32), 256, 0, stream>>>(queryb, wkE, qkb);
    gemm_atten<<<512, 256, 0, stream>>>(memb, qkb, content_e, rowsum, etb);
    combine<<<512, 256, 0, stream>>>(etb, bucket, boff, qkb,
                                     rowsum, out_logits, out);
}

// Round 13
// 100.427 us; speedup vs baseline: 1.2289x; 1.1190x over previous
//
#include <hip/hip_runtime.h>
#include <math.h>

#define BSZ   16
#define LSEQ  1024
#define TGT   256
#define HID   512
#define TV    2000
#define VOC   3000
#define SRC   2048
#define NKE   1280     // WkE rows: 2 j-halves x 640 (512 d + sentinel + bias + pad)
#define JOFF  640
#define SCALE 0.044194173824159216f   // 1/sqrt(512)

typedef unsigned short u16;
typedef __attribute__((ext_vector_type(8))) short bf16x8;
typedef __attribute__((ext_vector_type(4))) float f32x4;

__device__ __forceinline__ u16 f2bf(float x) {
    unsigned u = __float_as_uint(x);
    u += 0x7FFFu + ((u >> 16) & 1u);
    return (u16)(u >> 16);
}
__device__ __forceinline__ float bf2f(u16 x) {
    return __uint_as_float((unsigned)x << 16);
}

static __device__ __forceinline__ float gelu_exact(float x) {
    return 0.5f * x * (1.0f + erff(x * 0.70710678118654752f));
}

// async 16B global -> LDS (wave-uniform LDS base + lane*16)
__device__ __forceinline__ void gload16(const u16* g, u16* l) {
    __builtin_amdgcn_global_load_lds(
        (const __attribute__((address_space(1))) unsigned int*)g,
        (__attribute__((address_space(3))) unsigned int*)l,
        16, 0, 0);
}

// ---------------- PREP mega-kernel ----------------
// blocks: [0,4096) cast memory_raw | [4096,5120) cast feature | [5120,5376) Wq^T |
//         [5376,5696) WkE build | 5696 rowsum=0 | [5697,6721) logits LSE | [6721,6737) buckets
__device__ __forceinline__ void cast8_body(const float4* __restrict__ in,
                                           int4* __restrict__ out, int i) {
    float4 x = in[2 * i], y = in[2 * i + 1];
    unsigned p0 = (unsigned)f2bf(x.x) | ((unsigned)f2bf(x.y) << 16);
    unsigned p1 = (unsigned)f2bf(x.z) | ((unsigned)f2bf(x.w) << 16);
    unsigned p2 = (unsigned)f2bf(y.x) | ((unsigned)f2bf(y.y) << 16);
    unsigned p3 = (unsigned)f2bf(y.z) | ((unsigned)f2bf(y.w) << 16);
    out[i] = make_int4(p0, p1, p2, p3);
}

__global__ __launch_bounds__(256) void prep(
    const float* __restrict__ memory_raw, const float* __restrict__ feature,
    const float* __restrict__ Wq, const float* __restrict__ Wk,
    const float* __restrict__ sentinel, const float* __restrict__ bk,
    const float* __restrict__ logits, const int* __restrict__ ce,
    int4* __restrict__ memb, int4* __restrict__ featb,
    u16* __restrict__ wqT, u16* __restrict__ wkE,
    float* __restrict__ rowsum, float* __restrict__ lse,
    int* __restrict__ boff, u16* __restrict__ bucket)
{
    __shared__ float t[32][33];
    __shared__ int cnt[VOC];
    __shared__ int part[256];
    const int id = blockIdx.x;
    const int tid = threadIdx.x;
    if (id < 4096) {
        cast8_body((const float4*)memory_raw, memb, id * 256 + tid);
    } else if (id < 5120) {
        cast8_body((const float4*)feature, featb, (id - 4096) * 256 + tid);
    } else if (id < 5376) {
        // Wq^T (512x512)
        int id2 = id - 5120;
        int bx = (id2 & 15) * 32, by = (id2 >> 4) * 32;
        const int tx = tid & 31, ty = tid >> 5;
        #pragma unroll
        for (int k = 0; k < 4; ++k)
            t[ty + 8 * k][tx] = Wq[(size_t)(by + ty + 8 * k) * 512 + bx + tx];
        __syncthreads();
        #pragma unroll
        for (int k = 0; k < 4; ++k)
            wqT[(size_t)(bx + ty + 8 * k) * 512 + by + tx] = f2bf(t[tx][ty + 8 * k]);
    } else if (id < 5696) {
        // WkE build: 4 rows per block, 64 threads x 8 cols per row
        const int rr = (id - 5376) * 4 + (tid >> 6);   // 0..1279
        const int c = (tid & 63) * 8;
        const int j = rr >= JOFF;
        const int dd = rr - j * JOFF;
        u16* dst = wkE + (size_t)rr * HID + c;
        if (dd < 512) {
            const float* src = Wk + (size_t)dd * 1024 + j * 512 + c;
            #pragma unroll
            for (int k = 0; k < 8; ++k) dst[k] = f2bf(src[k]);
        } else if (dd == 512) {
            #pragma unroll
            for (int k = 0; k < 8; ++k) dst[k] = f2bf(sentinel[c + k]);
        } else if (dd == 513) {
            #pragma unroll
            for (int k = 0; k < 8; ++k) dst[k] = f2bf(bk[j * 512 + c + k]);
        } else {
            #pragma unroll
            for (int k = 0; k < 8; ++k) dst[k] = 0;
        }
    } else if (id == 5696) {
        // zero rowsum (4096 f32 = 1024 float4) — fresh every launch
        float4* rz = (float4*)rowsum;
        for (int i = tid; i < 1024; i += 256) rz[i] = make_float4(0.f, 0.f, 0.f, 0.f);
    } else if (id < 6721) {
        // logits LSE: 4 rows per block, one wave per row (TV = 500 float4)
        const int row = (id - 5697) * 4 + (tid >> 6);
        const int lane = tid & 63;
        const float4* lrow4 = (const float4*)(logits + (size_t)row * TV);
        float4 v4[8];
        float m = -INFINITY;
        #pragma unroll
        for (int k = 0; k < 8; ++k) {
            int idx = lane + 64 * k;
            if (idx < 500) {
                v4[k] = lrow4[idx];
                m = fmaxf(m, fmaxf(fmaxf(v4[k].x, v4[k].y), fmaxf(v4[k].z, v4[k].w)));
            } else {
                v4[k] = make_float4(-INFINITY, -INFINITY, -INFINITY, -INFINITY);
            }
        }
        #pragma unroll
        for (int o = 32; o > 0; o >>= 1) m = fmaxf(m, __shfl_xor(m, o, 64));
        float s = 0.f;
        #pragma unroll
        for (int k = 0; k < 8; ++k)
            s += __expf(v4[k].x - m) + __expf(v4[k].y - m)
               + __expf(v4[k].z - m) + __expf(v4[k].w - m);
        #pragma unroll
        for (int o = 32; o > 0; o >>= 1) s += __shfl_xor(s, o, 64);
        if (lane == 0) lse[row] = m + __logf(s);
    } else {
        // bucket build: one block per batch. buckets of jl-indices grouped by vocab id.
        const int b = id - 6721;
        const int* ceb = ce + (size_t)b * SRC;
        for (int v = tid; v < VOC; v += 256) cnt[v] = 0;
        __syncthreads();
        for (int s = tid; s < SRC; s += 256) atomicAdd(&cnt[ceb[s]], 1);
        __syncthreads();
        // block exclusive scan over cnt[3000] (each thread 12 bins)
        const int base = tid * 12;
        int lc[12];
        int tot = 0;
        #pragma unroll
        for (int k = 0; k < 12; ++k) {
            int v = base + k;
            lc[k] = (v < VOC) ? cnt[v] : 0;
            tot += lc[k];
        }
        part[tid] = tot;
        __syncthreads();
        for (int d = 1; d < 256; d <<= 1) {
            int val = (tid >= d) ? part[tid - d] : 0;
            __syncthreads();
            part[tid] += val;
            __syncthreads();
        }
        int run = part[tid] - tot;   // exclusive prefix
        int* boffb = boff + b * 3008;
        #pragma unroll
        for (int k = 0; k < 12; ++k) {
            int v = base + k;
            if (v < VOC) { boffb[v] = run; cnt[v] = run; run += lc[k]; }
        }
        if (tid == 0) boffb[VOC] = SRC;
        __syncthreads();
        for (int s = tid; s < SRC; s += 256) {
            int idv = ceb[s];
            int jl = (s & 1) * 1024 + (s >> 1);
            int pos = atomicAdd(&cnt[idv], 1);
            bucket[(size_t)b * SRC + pos] = (u16)jl;
        }
    }
}

// ---------------- query GEMM: 64x64 tile, BK=32 (512 blocks for TLP) ----------------
__global__ __launch_bounds__(256) void gemm_query(
    const u16* __restrict__ feat, const u16* __restrict__ wqT,
    const float* __restrict__ bq, u16* __restrict__ queryb)
{
    __shared__ u16 As[2 * 2048];
    __shared__ u16 Bs[2 * 2048];
    const int tid = threadIdx.x;
    const int lane = tid & 63;
    const int w = tid >> 6;
    const int wr = (w >> 1) * 32, wc = (w & 1) * 32;
    const int m0 = blockIdx.y * 64, n0 = blockIdx.x * 64;

    const int srow = tid >> 2, scol = (tid & 3) * 8;
    const u16* gA = feat + (size_t)(m0 + srow) * HID + scol;
    const u16* gB = wqT + (size_t)(n0 + srow) * HID + scol;

    const int la = lane & 15, lb = lane >> 4;
    f32x4 acc[2][2] = {};

    gload16(gA, As + w * 512);
    gload16(gB, Bs + w * 512);

    int cur = 0;
    for (int k0 = 0; k0 < HID; k0 += 32) {
        __syncthreads();   // drains vmcnt(0) + barrier
        const u16* Asb = As + cur * 2048;
        const u16* Bsb = Bs + cur * 2048;
        bf16x8 af[2], bf[2];
        #pragma unroll
        for (int i = 0; i < 2; ++i)
            af[i] = *(const bf16x8*)(Asb + (wr + i * 16 + la) * 32 + lb * 8);
        #pragma unroll
        for (int j = 0; j < 2; ++j)
            bf[j] = *(const bf16x8*)(Bsb + (wc + j * 16 + la) * 32 + lb * 8);
        if (k0 + 32 < HID) {
            const int nb = cur ^ 1;
            gload16(gA + k0 + 32, As + nb * 2048 + w * 512);
            gload16(gB + k0 + 32, Bs + nb * 2048 + w * 512);
        }
        #pragma unroll
        for (int i = 0; i < 2; ++i)
            #pragma unroll
            for (int j = 0; j < 2; ++j)
                acc[i][j] = __builtin_amdgcn_mfma_f32_16x16x32_bf16(af[i], bf[j], acc[i][j], 0, 0, 0);
        cur ^= 1;
    }

    const int r_l = (lane >> 4) * 4, c_l = lane & 15;
    #pragma unroll
    for (int j = 0; j < 2; ++j) {
        const int n = n0 + wc + j * 16 + c_l;
        const float bv = bq[n];
        #pragma unroll
        for (int i = 0; i < 2; ++i)
            #pragma unroll
            for (int r = 0; r < 4; ++r) {
                const int m = m0 + wr + i * 16 + r_l + r;
                queryb[(size_t)m * HID + n] = f2bf(gelu_exact(acc[i][j][r] + bv));
            }
    }
}

// ---------------- MFMA GEMM body (128x128, BK=32) for qk and atten ----------------
// EPI 3: qk (plain)  -> bf16 [m][1280]
// EPI 2: atten TRANSPOSED: A=mem rows l, B=qk rows t. out E_T[b][jl][t]=exp bf16;
//        per-col sums atomically into rowsum. z=(b,jj)
template<int EPI, int LDA, int LDB>
__device__ __forceinline__ void gemm_body(
    int m0, int n0, int z,
    const u16* __restrict__ Abase, const u16* __restrict__ Bbase,
    u16* __restrict__ outb,
    const int* __restrict__ ce, float* __restrict__ rowsum,
    u16* __restrict__ As, u16* __restrict__ Bs)   // each 2*4096 u16
{
    const int tid = threadIdx.x;
    const int lane = tid & 63;
    const int w = tid >> 6;
    const int wr = (w >> 1) * 64, wc = (w & 1) * 64;

    const u16* Ag = Abase;
    const u16* Bg = Bbase;
    if (EPI == 2) {
        Ag = Abase + (size_t)(z >> 1) * LSEQ * HID;                        // memb[b]
        Bg = Bbase + (size_t)(z >> 1) * TGT * NKE + (size_t)(z & 1) * JOFF; // qk[b], jj half
    }

    const int chunkrow = lane >> 2;
    const int colc = (lane & 3) * 8;
    const int c0 = w * 2, c1 = c0 + 1;
    const u16* gA0 = Ag + (size_t)(m0 + c0 * 16 + chunkrow) * LDA + colc;
    const u16* gA1 = Ag + (size_t)(m0 + c1 * 16 + chunkrow) * LDA + colc;
    const u16* gB0 = Bg + (size_t)(n0 + c0 * 16 + chunkrow) * LDB + colc;
    const u16* gB1 = Bg + (size_t)(n0 + c1 * 16 + chunkrow) * LDB + colc;

    const int la = lane & 15, lb = lane >> 4;
    f32x4 acc[4][4] = {};

    gload16(gA0, As + c0 * 512);
    gload16(gA1, As + c1 * 512);
    gload16(gB0, Bs + c0 * 512);
    gload16(gB1, Bs + c1 * 512);

    int cur = 0;
    for (int k0 = 0; k0 < HID; k0 += 32) {
        __syncthreads();   // drains vmcnt(0) (stage complete) + barrier
        const u16* Asb = As + cur * 4096;
        const u16* Bsb = Bs + cur * 4096;
        bf16x8 af[4], bfv[4];
        #pragma unroll
        for (int i = 0; i < 4; ++i)
            af[i] = *(const bf16x8*)(Asb + (wr + i * 16 + la) * 32 + lb * 8);
        #pragma unroll
        for (int j = 0; j < 4; ++j)
            bfv[j] = *(const bf16x8*)(Bsb + (wc + j * 16 + la) * 32 + lb * 8);
        if (k0 + 32 < HID) {
            const int nb = cur ^ 1;
            u16* An = As + nb * 4096;
            u16* Bn = Bs + nb * 4096;
            gload16(gA0 + k0 + 32, An + c0 * 512);
            gload16(gA1 + k0 + 32, An + c1 * 512);
            gload16(gB0 + k0 + 32, Bn + c0 * 512);
            gload16(gB1 + k0 + 32, Bn + c1 * 512);
        }
        #pragma unroll
        for (int i = 0; i < 4; ++i)
            #pragma unroll
            for (int j = 0; j < 4; ++j)
                acc[i][j] = __builtin_amdgcn_mfma_f32_16x16x32_bf16(af[i], bfv[j], acc[i][j], 0, 0, 0);
        cur ^= 1;
    }

    const int r_l = (lane >> 4) * 4, c_l = lane & 15;
    if (EPI == 3) {
        #pragma unroll
        for (int j = 0; j < 4; ++j) {
            const int n = n0 + wc + j * 16 + c_l;
            #pragma unroll
            for (int i = 0; i < 4; ++i)
                #pragma unroll
                for (int r = 0; r < 4; ++r) {
                    const int m = m0 + wr + i * 16 + r_l + r;
                    outb[(size_t)m * NKE + n] = f2bf(acc[i][j][r]);
                }
        }
    } else {
        const int b = z >> 1, jj = z & 1;
        // per-col (t) bias = q.bk_j gathered from qk; per-row (l) mask from raw ce
        float biasc[4];
        #pragma unroll
        for (int j = 0; j < 4; ++j) {
            const int n = n0 + wc + j * 16 + c_l;   // t
            biasc[j] = bf2f(Bbase[(size_t)(b * TGT + n) * NKE + jj * JOFF + 513]);
        }
        const int* ceb = ce + (size_t)b * SRC;
        float csum[4] = {0.f, 0.f, 0.f, 0.f};
        #pragma unroll
        for (int i = 0; i < 4; ++i)
            #pragma unroll
            for (int r = 0; r < 4; ++r) {
                const int m = m0 + wr + i * 16 + r_l + r;      // l
                const int cm = ceb[2 * m + jj];
                const size_t rowbase = ((size_t)b * SRC + jj * 1024 + m) * TGT;
                #pragma unroll
                for (int j = 0; j < 4; ++j) {
                    float ev = (cm == 0) ? 0.f
                             : __expf((acc[i][j][r] + biasc[j]) * SCALE);
                    outb[rowbase + n0 + wc + j * 16 + c_l] = f2bf(ev);
                    csum[j] += ev;
                }
            }
        #pragma unroll
        for (int j = 0; j < 4; ++j) {
            csum[j] += __shfl_xor(csum[j], 16, 64);
            csum[j] += __shfl_xor(csum[j], 32, 64);
        }
        const int jsel = lane >> 4;
        float myv = (jsel == 0) ? csum[0] : (jsel == 1) ? csum[1]
                  : (jsel == 2) ? csum[2] : csum[3];
        atomicAdd(&rowsum[b * TGT + n0 + wc + jsel * 16 + c_l], myv);
    }
}

__global__ __launch_bounds__(256) void gemm_qk(
    const u16* __restrict__ queryb, const u16* __restrict__ wkE,
    u16* __restrict__ qkb)
{
    __shared__ u16 As[2 * 4096];
    __shared__ u16 Bs[2 * 4096];
    gemm_body<3, 512, 512>(blockIdx.y * 128, blockIdx.x * 128, 0,
                           queryb, wkE, qkb, nullptr, nullptr, As, Bs);
}

// atten: 512 blocks = 32 (b,jj) x 16 inner tiles, XCD-grouped:
// all 16 inner tiles of a (b,jj) share i&7 -> one XCD's L2.
__global__ __launch_bounds__(256) void gemm_atten(
    const u16* __restrict__ memb, const u16* __restrict__ qkb,
    const int* __restrict__ ce, float* __restrict__ rowsum,
    u16* __restrict__ etb)
{
    __shared__ u16 As[2 * 4096];
    __shared__ u16 Bs[2 * 4096];
    const int i = blockIdx.x;
    const int xcd = i & 7, slot = i >> 3;        // slot in [0,64)
    const int bjj = xcd + 8 * (slot >> 4);       // [0,32) = b*2+jj
    const int inner = slot & 15;                 // 8 l-tiles x 2 t-tiles
    gemm_body<2, 512, NKE>((inner >> 1) * 128, (inner & 1) * 128, bjj,
                           memb, qkb, etb, ce, rowsum, As, Bs);
}

// ---------------- combine-v3: (b, tc, vg) grid, precomputed LSE, conflict-free LDS ----------------
// 1536 blocks = 16 b x 32 tc x 3 vg, XCD-grouped per batch.
__global__ __launch_bounds__(256) void combine(
    const u16* __restrict__ etb, const u16* __restrict__ bucket,
    const int* __restrict__ boff, const u16* __restrict__ qkb,
    const float* __restrict__ rowsum, const float* __restrict__ lse,
    const float* __restrict__ out_logits, float* __restrict__ out)
{
    __shared__ float acc[8][256];   // [t-local][v-local]
    __shared__ float rcInv[8], rcGZ[8], rcEdl[8], rcDl[8];
    const int i = blockIdx.x;
    const int xcd = i & 7, slot = i >> 3;      // slot in [0,192)
    const int b = xcd + 8 * (slot / 96);       // all 96 blocks of b on one XCD
    const int inner = slot % 96;
    const int tc = inner / 3, vg = inner % 3;
    const int t0 = tc * 8;
    const int tid = threadIdx.x;
    const float EPSF = 1.1920929e-07f;

    // row constants from precomputed lse + rowsum (no logits read here)
    if (tid < 8) {
        const int bt = b * TGT + t0 + tid;
        const float sent_v = bf2f(qkb[(size_t)bt * NKE + 512]) * SCALE;
        const float se = __expf(sent_v);
        const float sm = rowsum[bt] + se;
        const float inv = 1.0f / sm;
        const float g = sent_v - __logf(sm);
        const float eg = se * inv;
        const float dl = __logf(1.0f - eg + EPSF) - log1pf(-eg + EPSF);
        rcInv[tid] = inv;
        rcGZ[tid] = g - lse[bt];
        rcEdl[tid] = __expf(dl);
        rcDl[tid] = dl;
    }

    const int* boffb = boff + b * 3008;
    const u16* bukb = bucket + (size_t)b * SRC;
    const u16* etbb = etb + (size_t)b * SRC * TGT;
    #pragma unroll
    for (int vc = 0; vc < 4; ++vc) {
        const int vbase = vg * 1024 + vc * 256;
        __syncthreads();   // rc* visible (vc=0); prev-chunk readers done (vc>0)
        // gather: thread owns v = vbase + tid
        {
            float a[8] = {0.f, 0.f, 0.f, 0.f, 0.f, 0.f, 0.f, 0.f};
            const int v = vbase + tid;
            if (v < VOC) {
                const int e0 = boffb[v], e1 = boffb[v + 1];
                for (int e = e0; e < e1; ++e) {
                    const int s = bukb[e];
                    int4 u = *(const int4*)(etbb + (size_t)s * TGT + t0);
                    a[0] += bf2f((u16)(u.x & 0xffff));
                    a[1] += bf2f((u16)((unsigned)u.x >> 16));
                    a[2] += bf2f((u16)(u.y & 0xffff));
                    a[3] += bf2f((u16)((unsigned)u.y >> 16));
                    a[4] += bf2f((u16)(u.z & 0xffff));
                    a[5] += bf2f((u16)((unsigned)u.z >> 16));
                    a[6] += bf2f((u16)(u.w & 0xffff));
                    a[7] += bf2f((u16)((unsigned)u.w >> 16));
                }
            }
            #pragma unroll
            for (int k = 0; k < 8; ++k) acc[k][tid] = a[k];
        }
        __syncthreads();
        // output: r = tid>>5; 8 lane-strided v per thread (conflict-free LDS, coalesced stores)
        const int r = tid >> 5;
        const int vl0 = tid & 31;
        const int bt = b * TGT + t0 + r;
        const float inv = rcInv[r], gZ = rcGZ[r], edl = rcEdl[r], dlv = rcDl[r];
        const float* lrow = out_logits + (size_t)bt * TV;
        float* orow = out + (size_t)bt * VOC;
        #pragma unroll
        for (int kk = 0; kk < 8; ++kk) {
            const int vloc = vl0 + 32 * kk;
            const int v = vbase + vloc;
            if (v >= VOC) continue;
            float pv = acc[r][vloc] * inv + EPSF;
            float o;
            if (v < TV) o = __logf(__expf(lrow[v] + gZ) + pv * edl);
            else        o = __logf(pv) + dlv;
            orow[v] = o;
        }
    }
}

extern "C" void kernel_launch(void* const* d_in, const int* in_sizes, int n_in,
                              void* d_out, int out_size, void* d_ws, size_t ws_size,
                              hipStream_t stream) {
    const float* out_logits = (const float*)d_in[0];
    const float* feature    = (const float*)d_in[1];
    const float* memory_raw = (const float*)d_in[2];
    const int*   content_e  = (const int*)d_in[3];
    const float* Wq = (const float*)d_in[4];
    const float* bq = (const float*)d_in[5];
    const float* Wk = (const float*)d_in[6];
    const float* bk = (const float*)d_in[7];
    const float* sentinel = (const float*)d_in[8];
    float* out = (float*)d_out;

    u16* memb   = (u16*)d_ws;                             // 16384*512 bf16
    u16* featb  = memb   + (size_t)16384 * 512;           // 4096*512
    u16* wqT    = featb  + (size_t)4096 * 512;            // 512*512
    u16* wkE    = wqT    + (size_t)512 * 512;             // 1280*512
    u16* queryb = wkE    + (size_t)NKE * 512;             // 4096*512
    u16* qkb    = queryb + (size_t)4096 * 512;            // 4096*1280
    u16* etb    = qkb    + (size_t)4096 * NKE;            // 16*2048*256 bf16 E^T
    float* rowsum = (float*)(etb + (size_t)BSZ * SRC * TGT); // 4096 f32
    float* lse   = rowsum + 4096;                         // 4096 f32
    int* boff = (int*)(lse + 4096);                       // 16*3008 int
    u16* bucket = (u16*)(boff + 16 * 3008);               // 16*2048 u16

    prep<<<6737, 256, 0, stream>>>(memory_raw, feature, Wq, Wk, sentinel, bk,
                                   out_logits, content_e,
                                   (int4*)memb, (int4*)featb, wqT, wkE,
                                   rowsum, lse, boff, bucket);
    gemm_query<<<dim3(8, 64), 256, 0, stream>>>(featb, wqT, bq, queryb);
    gemm_qk<<<dim3(10, 32), 256, 0, stream>>>(queryb, wkE, qkb);
    gemm_atten<<<512, 256, 0, stream>>>(memb, qkb, content_e, rowsum, etb);
    combine<<<1536, 256, 0, stream>>>(etb, bucket, boff, qkb,
                                      rowsum, lse, out_logits, out);
}

// Round 14
// 98.075 us; speedup vs baseline: 1.2583x; 1.0240x over previous
//
#include <hip/hip_runtime.h>
#include <math.h>

#define BSZ   16
#define LSEQ  1024
#define TGT   256
#define HID   512
#define TV    2000
#define VOC   3000
#define SRC   2048
#define NKE   1280     // WkE rows: 2 j-halves x 640 (512 d + sentinel + bias + pad)
#define JOFF  640
#define SCALE 0.044194173824159216f   // 1/sqrt(512)

typedef unsigned short u16;
typedef __attribute__((ext_vector_type(8))) short bf16x8;
typedef __attribute__((ext_vector_type(4))) float f32x4;

__device__ __forceinline__ u16 f2bf(float x) {
    unsigned u = __float_as_uint(x);
    u += 0x7FFFu + ((u >> 16) & 1u);
    return (u16)(u >> 16);
}
__device__ __forceinline__ float bf2f(u16 x) {
    return __uint_as_float((unsigned)x << 16);
}

static __device__ __forceinline__ float gelu_exact(float x) {
    return 0.5f * x * (1.0f + erff(x * 0.70710678118654752f));
}

// async 16B global -> LDS (wave-uniform LDS base + lane*16)
__device__ __forceinline__ void gload16(const u16* g, u16* l) {
    __builtin_amdgcn_global_load_lds(
        (const __attribute__((address_space(1))) unsigned int*)g,
        (__attribute__((address_space(3))) unsigned int*)l,
        16, 0, 0);
}

// ---------------- PREP mega-kernel ----------------
// blocks: [0,4096) cast memory_raw | [4096,5120) cast feature | [5120,5376) Wq^T |
//         [5376,5696) WkE build | 5696 rowsum=0 | [5697,6721) logits LSE | [6721,6737) buckets
__device__ __forceinline__ void cast8_body(const float4* __restrict__ in,
                                           int4* __restrict__ out, int i) {
    float4 x = in[2 * i], y = in[2 * i + 1];
    unsigned p0 = (unsigned)f2bf(x.x) | ((unsigned)f2bf(x.y) << 16);
    unsigned p1 = (unsigned)f2bf(x.z) | ((unsigned)f2bf(x.w) << 16);
    unsigned p2 = (unsigned)f2bf(y.x) | ((unsigned)f2bf(y.y) << 16);
    unsigned p3 = (unsigned)f2bf(y.z) | ((unsigned)f2bf(y.w) << 16);
    out[i] = make_int4(p0, p1, p2, p3);
}

__global__ __launch_bounds__(256) void prep(
    const float* __restrict__ memory_raw, const float* __restrict__ feature,
    const float* __restrict__ Wq, const float* __restrict__ Wk,
    const float* __restrict__ sentinel, const float* __restrict__ bk,
    const float* __restrict__ logits, const int* __restrict__ ce,
    int4* __restrict__ memb, int4* __restrict__ featb,
    u16* __restrict__ wqT, u16* __restrict__ wkE,
    float* __restrict__ rowsum, float* __restrict__ lse,
    int* __restrict__ boff, u16* __restrict__ bucket)
{
    __shared__ float t[32][33];
    __shared__ int cnt[VOC];
    __shared__ int part[256];
    const int id = blockIdx.x;
    const int tid = threadIdx.x;
    if (id < 4096) {
        cast8_body((const float4*)memory_raw, memb, id * 256 + tid);
    } else if (id < 5120) {
        cast8_body((const float4*)feature, featb, (id - 4096) * 256 + tid);
    } else if (id < 5376) {
        // Wq^T (512x512)
        int id2 = id - 5120;
        int bx = (id2 & 15) * 32, by = (id2 >> 4) * 32;
        const int tx = tid & 31, ty = tid >> 5;
        #pragma unroll
        for (int k = 0; k < 4; ++k)
            t[ty + 8 * k][tx] = Wq[(size_t)(by + ty + 8 * k) * 512 + bx + tx];
        __syncthreads();
        #pragma unroll
        for (int k = 0; k < 4; ++k)
            wqT[(size_t)(bx + ty + 8 * k) * 512 + by + tx] = f2bf(t[tx][ty + 8 * k]);
    } else if (id < 5696) {
        // WkE build: 4 rows per block, 64 threads x 8 cols per row
        const int rr = (id - 5376) * 4 + (tid >> 6);   // 0..1279
        const int c = (tid & 63) * 8;
        const int j = rr >= JOFF;
        const int dd = rr - j * JOFF;
        u16* dst = wkE + (size_t)rr * HID + c;
        if (dd < 512) {
            const float* src = Wk + (size_t)dd * 1024 + j * 512 + c;
            #pragma unroll
            for (int k = 0; k < 8; ++k) dst[k] = f2bf(src[k]);
        } else if (dd == 512) {
            #pragma unroll
            for (int k = 0; k < 8; ++k) dst[k] = f2bf(sentinel[c + k]);
        } else if (dd == 513) {
            #pragma unroll
            for (int k = 0; k < 8; ++k) dst[k] = f2bf(bk[j * 512 + c + k]);
        } else {
            #pragma unroll
            for (int k = 0; k < 8; ++k) dst[k] = 0;
        }
    } else if (id == 5696) {
        // zero rowsum (4096 f32 = 1024 float4) — fresh every launch
        float4* rz = (float4*)rowsum;
        for (int i = tid; i < 1024; i += 256) rz[i] = make_float4(0.f, 0.f, 0.f, 0.f);
    } else if (id < 6721) {
        // logits LSE: 4 rows per block, one wave per row (TV = 500 float4)
        const int row = (id - 5697) * 4 + (tid >> 6);
        const int lane = tid & 63;
        const float4* lrow4 = (const float4*)(logits + (size_t)row * TV);
        float4 v4[8];
        float m = -INFINITY;
        #pragma unroll
        for (int k = 0; k < 8; ++k) {
            int idx = lane + 64 * k;
            if (idx < 500) {
                v4[k] = lrow4[idx];
                m = fmaxf(m, fmaxf(fmaxf(v4[k].x, v4[k].y), fmaxf(v4[k].z, v4[k].w)));
            } else {
                v4[k] = make_float4(-INFINITY, -INFINITY, -INFINITY, -INFINITY);
            }
        }
        #pragma unroll
        for (int o = 32; o > 0; o >>= 1) m = fmaxf(m, __shfl_xor(m, o, 64));
        float s = 0.f;
        #pragma unroll
        for (int k = 0; k < 8; ++k)
            s += __expf(v4[k].x - m) + __expf(v4[k].y - m)
               + __expf(v4[k].z - m) + __expf(v4[k].w - m);
        #pragma unroll
        for (int o = 32; o > 0; o >>= 1) s += __shfl_xor(s, o, 64);
        if (lane == 0) lse[row] = m + __logf(s);
    } else {
        // bucket build: one block per batch. buckets of jl-indices grouped by vocab id.
        const int b = id - 6721;
        const int* ceb = ce + (size_t)b * SRC;
        for (int v = tid; v < VOC; v += 256) cnt[v] = 0;
        __syncthreads();
        for (int s = tid; s < SRC; s += 256) atomicAdd(&cnt[ceb[s]], 1);
        __syncthreads();
        // block exclusive scan over cnt[3000] (each thread 12 bins)
        const int base = tid * 12;
        int lc[12];
        int tot = 0;
        #pragma unroll
        for (int k = 0; k < 12; ++k) {
            int v = base + k;
            lc[k] = (v < VOC) ? cnt[v] : 0;
            tot += lc[k];
        }
        part[tid] = tot;
        __syncthreads();
        for (int d = 1; d < 256; d <<= 1) {
            int val = (tid >= d) ? part[tid - d] : 0;
            __syncthreads();
            part[tid] += val;
            __syncthreads();
        }
        int run = part[tid] - tot;   // exclusive prefix
        int* boffb = boff + b * 3008;
        #pragma unroll
        for (int k = 0; k < 12; ++k) {
            int v = base + k;
            if (v < VOC) { boffb[v] = run; cnt[v] = run; run += lc[k]; }
        }
        if (tid == 0) boffb[VOC] = SRC;
        __syncthreads();
        for (int s = tid; s < SRC; s += 256) {
            int idv = ceb[s];
            int jl = (s & 1) * 1024 + (s >> 1);
            int pos = atomicAdd(&cnt[idv], 1);
            bucket[(size_t)b * SRC + pos] = (u16)jl;
        }
    }
}

// ---------------- query GEMM: 64x64 tile, BK=32 (512 blocks for TLP) ----------------
__global__ __launch_bounds__(256) void gemm_query(
    const u16* __restrict__ feat, const u16* __restrict__ wqT,
    const float* __restrict__ bq, u16* __restrict__ queryb)
{
    __shared__ u16 As[2 * 2048];
    __shared__ u16 Bs[2 * 2048];
    const int tid = threadIdx.x;
    const int lane = tid & 63;
    const int w = tid >> 6;
    const int wr = (w >> 1) * 32, wc = (w & 1) * 32;
    const int m0 = blockIdx.y * 64, n0 = blockIdx.x * 64;

    const int srow = tid >> 2, scol = (tid & 3) * 8;
    const u16* gA = feat + (size_t)(m0 + srow) * HID + scol;
    const u16* gB = wqT + (size_t)(n0 + srow) * HID + scol;

    const int la = lane & 15, lb = lane >> 4;
    f32x4 acc[2][2] = {};

    gload16(gA, As + w * 512);
    gload16(gB, Bs + w * 512);

    int cur = 0;
    for (int k0 = 0; k0 < HID; k0 += 32) {
        __syncthreads();   // drains vmcnt(0) + barrier
        const u16* Asb = As + cur * 2048;
        const u16* Bsb = Bs + cur * 2048;
        bf16x8 af[2], bf[2];
        #pragma unroll
        for (int i = 0; i < 2; ++i)
            af[i] = *(const bf16x8*)(Asb + (wr + i * 16 + la) * 32 + lb * 8);
        #pragma unroll
        for (int j = 0; j < 2; ++j)
            bf[j] = *(const bf16x8*)(Bsb + (wc + j * 16 + la) * 32 + lb * 8);
        if (k0 + 32 < HID) {
            const int nb = cur ^ 1;
            gload16(gA + k0 + 32, As + nb * 2048 + w * 512);
            gload16(gB + k0 + 32, Bs + nb * 2048 + w * 512);
        }
        #pragma unroll
        for (int i = 0; i < 2; ++i)
            #pragma unroll
            for (int j = 0; j < 2; ++j)
                acc[i][j] = __builtin_amdgcn_mfma_f32_16x16x32_bf16(af[i], bf[j], acc[i][j], 0, 0, 0);
        cur ^= 1;
    }

    const int r_l = (lane >> 4) * 4, c_l = lane & 15;
    #pragma unroll
    for (int j = 0; j < 2; ++j) {
        const int n = n0 + wc + j * 16 + c_l;
        const float bv = bq[n];
        #pragma unroll
        for (int i = 0; i < 2; ++i)
            #pragma unroll
            for (int r = 0; r < 4; ++r) {
                const int m = m0 + wr + i * 16 + r_l + r;
                queryb[(size_t)m * HID + n] = f2bf(gelu_exact(acc[i][j][r] + bv));
            }
    }
}

// ---------------- MFMA GEMM body (128x128, BK=32) for qk and atten ----------------
// EPI 3: qk (plain)  -> bf16 [m][1280]
// EPI 2: atten TRANSPOSED: A=mem rows l, B=qk rows t. out E_T[b][jl][t]=exp bf16;
//        per-col sums atomically into rowsum. z=(b,jj)
template<int EPI, int LDA, int LDB>
__device__ __forceinline__ void gemm_body(
    int m0, int n0, int z,
    const u16* __restrict__ Abase, const u16* __restrict__ Bbase,
    u16* __restrict__ outb,
    const int* __restrict__ ce, float* __restrict__ rowsum,
    u16* __restrict__ As, u16* __restrict__ Bs)   // each 2*4096 u16
{
    const int tid = threadIdx.x;
    const int lane = tid & 63;
    const int w = tid >> 6;
    const int wr = (w >> 1) * 64, wc = (w & 1) * 64;

    const u16* Ag = Abase;
    const u16* Bg = Bbase;
    if (EPI == 2) {
        Ag = Abase + (size_t)(z >> 1) * LSEQ * HID;                        // memb[b]
        Bg = Bbase + (size_t)(z >> 1) * TGT * NKE + (size_t)(z & 1) * JOFF; // qk[b], jj half
    }

    const int chunkrow = lane >> 2;
    const int colc = (lane & 3) * 8;
    const int c0 = w * 2, c1 = c0 + 1;
    const u16* gA0 = Ag + (size_t)(m0 + c0 * 16 + chunkrow) * LDA + colc;
    const u16* gA1 = Ag + (size_t)(m0 + c1 * 16 + chunkrow) * LDA + colc;
    const u16* gB0 = Bg + (size_t)(n0 + c0 * 16 + chunkrow) * LDB + colc;
    const u16* gB1 = Bg + (size_t)(n0 + c1 * 16 + chunkrow) * LDB + colc;

    const int la = lane & 15, lb = lane >> 4;
    f32x4 acc[4][4] = {};

    gload16(gA0, As + c0 * 512);
    gload16(gA1, As + c1 * 512);
    gload16(gB0, Bs + c0 * 512);
    gload16(gB1, Bs + c1 * 512);

    int cur = 0;
    for (int k0 = 0; k0 < HID; k0 += 32) {
        __syncthreads();   // drains vmcnt(0) (stage complete) + barrier
        const u16* Asb = As + cur * 4096;
        const u16* Bsb = Bs + cur * 4096;
        bf16x8 af[4], bfv[4];
        #pragma unroll
        for (int i = 0; i < 4; ++i)
            af[i] = *(const bf16x8*)(Asb + (wr + i * 16 + la) * 32 + lb * 8);
        #pragma unroll
        for (int j = 0; j < 4; ++j)
            bfv[j] = *(const bf16x8*)(Bsb + (wc + j * 16 + la) * 32 + lb * 8);
        if (k0 + 32 < HID) {
            const int nb = cur ^ 1;
            u16* An = As + nb * 4096;
            u16* Bn = Bs + nb * 4096;
            gload16(gA0 + k0 + 32, An + c0 * 512);
            gload16(gA1 + k0 + 32, An + c1 * 512);
            gload16(gB0 + k0 + 32, Bn + c0 * 512);
            gload16(gB1 + k0 + 32, Bn + c1 * 512);
        }
        #pragma unroll
        for (int i = 0; i < 4; ++i)
            #pragma unroll
            for (int j = 0; j < 4; ++j)
                acc[i][j] = __builtin_amdgcn_mfma_f32_16x16x32_bf16(af[i], bfv[j], acc[i][j], 0, 0, 0);
        cur ^= 1;
    }

    const int r_l = (lane >> 4) * 4, c_l = lane & 15;
    if (EPI == 3) {
        #pragma unroll
        for (int j = 0; j < 4; ++j) {
            const int n = n0 + wc + j * 16 + c_l;
            #pragma unroll
            for (int i = 0; i < 4; ++i)
                #pragma unroll
                for (int r = 0; r < 4; ++r) {
                    const int m = m0 + wr + i * 16 + r_l + r;
                    outb[(size_t)m * NKE + n] = f2bf(acc[i][j][r]);
                }
        }
    } else {
        const int b = z >> 1, jj = z & 1;
        // per-col (t) bias = q.bk_j gathered from qk; per-row (l) mask from raw ce
        float biasc[4];
        #pragma unroll
        for (int j = 0; j < 4; ++j) {
            const int n = n0 + wc + j * 16 + c_l;   // t
            biasc[j] = bf2f(Bbase[(size_t)(b * TGT + n) * NKE + jj * JOFF + 513]);
        }
        const int* ceb = ce + (size_t)b * SRC;
        float csum[4] = {0.f, 0.f, 0.f, 0.f};
        #pragma unroll
        for (int i = 0; i < 4; ++i)
            #pragma unroll
            for (int r = 0; r < 4; ++r) {
                const int m = m0 + wr + i * 16 + r_l + r;      // l
                const int cm = ceb[2 * m + jj];
                const size_t rowbase = ((size_t)b * SRC + jj * 1024 + m) * TGT;
                #pragma unroll
                for (int j = 0; j < 4; ++j) {
                    float ev = (cm == 0) ? 0.f
                             : __expf((acc[i][j][r] + biasc[j]) * SCALE);
                    outb[rowbase + n0 + wc + j * 16 + c_l] = f2bf(ev);
                    csum[j] += ev;
                }
            }
        #pragma unroll
        for (int j = 0; j < 4; ++j) {
            csum[j] += __shfl_xor(csum[j], 16, 64);
            csum[j] += __shfl_xor(csum[j], 32, 64);
        }
        const int jsel = lane >> 4;
        float myv = (jsel == 0) ? csum[0] : (jsel == 1) ? csum[1]
                  : (jsel == 2) ? csum[2] : csum[3];
        atomicAdd(&rowsum[b * TGT + n0 + wc + jsel * 16 + c_l], myv);
    }
}

__global__ __launch_bounds__(256) void gemm_qk(
    const u16* __restrict__ queryb, const u16* __restrict__ wkE,
    u16* __restrict__ qkb)
{
    __shared__ u16 As[2 * 4096];
    __shared__ u16 Bs[2 * 4096];
    gemm_body<3, 512, 512>(blockIdx.y * 128, blockIdx.x * 128, 0,
                           queryb, wkE, qkb, nullptr, nullptr, As, Bs);
}

// atten: 512 blocks = 32 (b,jj) x 16 inner tiles, XCD-grouped:
// all 16 inner tiles of a (b,jj) share i&7 -> one XCD's L2.
__global__ __launch_bounds__(256) void gemm_atten(
    const u16* __restrict__ memb, const u16* __restrict__ qkb,
    const int* __restrict__ ce, float* __restrict__ rowsum,
    u16* __restrict__ etb)
{
    __shared__ u16 As[2 * 4096];
    __shared__ u16 Bs[2 * 4096];
    const int i = blockIdx.x;
    const int xcd = i & 7, slot = i >> 3;        // slot in [0,64)
    const int bjj = xcd + 8 * (slot >> 4);       // [0,32) = b*2+jj
    const int inner = slot & 15;                 // 8 l-tiles x 2 t-tiles
    gemm_body<2, 512, NKE>((inner >> 1) * 128, (inner & 1) * 128, bjj,
                           memb, qkb, etb, ce, rowsum, As, Bs);
}

// ---------------- combine-v4: one 256-v chunk per block, LDS-staged bucket slice ----------------
// 6144 blocks = 16 b x 32 tc x 12 vs, XCD-grouped per batch.
__global__ __launch_bounds__(256) void combine(
    const u16* __restrict__ etb, const u16* __restrict__ bucket,
    const int* __restrict__ boff, const u16* __restrict__ qkb,
    const float* __restrict__ rowsum, const float* __restrict__ lse,
    const float* __restrict__ out_logits, float* __restrict__ out)
{
    __shared__ float acc[8][256];   // [t-local][v-local]
    __shared__ u16 sbuck[SRC];      // staged bucket slice (worst case all entries)
    __shared__ float rcInv[8], rcGZ[8], rcEdl[8], rcDl[8];
    const int i = blockIdx.x;
    const int xcd = i & 7, slot = i >> 3;      // slot in [0,768)
    const int b = xcd + 8 * (slot / 384);      // all 384 blocks of b on one XCD
    const int inner = slot % 384;
    const int tc = inner / 12, vs = inner % 12;
    const int t0 = tc * 8;
    const int vbase = vs * 256;
    const int tid = threadIdx.x;
    const float EPSF = 1.1920929e-07f;

    // row constants from precomputed lse + rowsum
    if (tid < 8) {
        const int bt = b * TGT + t0 + tid;
        const float sent_v = bf2f(qkb[(size_t)bt * NKE + 512]) * SCALE;
        const float se = __expf(sent_v);
        const float sm = rowsum[bt] + se;
        const float inv = 1.0f / sm;
        const float g = sent_v - __logf(sm);
        const float eg = se * inv;
        const float dl = __logf(1.0f - eg + EPSF) - log1pf(-eg + EPSF);
        rcInv[tid] = inv;
        rcGZ[tid] = g - lse[bt];
        rcEdl[tid] = __expf(dl);
        rcDl[tid] = dl;
    }

    const int* boffb = boff + b * 3008;
    const u16* bukb = bucket + (size_t)b * SRC;
    const u16* etbb = etb + (size_t)b * SRC * TGT;

    // stage this chunk's bucket slice into LDS (contiguous, coalesced)
    const int vend = (vbase + 256 < VOC) ? vbase + 256 : VOC;
    const int e_lo = boffb[vbase];
    const int e_hi = boffb[vend];
    for (int e = e_lo + tid; e < e_hi; e += 256) sbuck[e - e_lo] = bukb[e];
    __syncthreads();

    // gather: thread owns v = vbase + tid; entries read from LDS, etb loads pipeline
    {
        float a[8] = {0.f, 0.f, 0.f, 0.f, 0.f, 0.f, 0.f, 0.f};
        const int v = vbase + tid;
        if (v < VOC) {
            const int i0 = boffb[v] - e_lo;
            const int i1 = boffb[v + 1] - e_lo;
            for (int e = i0; e < i1; ++e) {
                const int s = sbuck[e];
                int4 u = *(const int4*)(etbb + (size_t)s * TGT + t0);
                a[0] += bf2f((u16)(u.x & 0xffff));
                a[1] += bf2f((u16)((unsigned)u.x >> 16));
                a[2] += bf2f((u16)(u.y & 0xffff));
                a[3] += bf2f((u16)((unsigned)u.y >> 16));
                a[4] += bf2f((u16)(u.z & 0xffff));
                a[5] += bf2f((u16)((unsigned)u.z >> 16));
                a[6] += bf2f((u16)(u.w & 0xffff));
                a[7] += bf2f((u16)((unsigned)u.w >> 16));
            }
        }
        #pragma unroll
        for (int k = 0; k < 8; ++k) acc[k][tid] = a[k];
    }
    __syncthreads();

    // output: r = tid>>5; 8 lane-strided v per thread (conflict-free LDS, coalesced stores)
    const int r = tid >> 5;
    const int vl0 = tid & 31;
    const int bt = b * TGT + t0 + r;
    const float inv = rcInv[r], gZ = rcGZ[r], edl = rcEdl[r], dlv = rcDl[r];
    const float* lrow = out_logits + (size_t)bt * TV;
    float* orow = out + (size_t)bt * VOC;
    #pragma unroll
    for (int kk = 0; kk < 8; ++kk) {
        const int vloc = vl0 + 32 * kk;
        const int v = vbase + vloc;
        if (v >= VOC) continue;
        float pv = acc[r][vloc] * inv + EPSF;
        float o;
        if (v < TV) o = __logf(__expf(lrow[v] + gZ) + pv * edl);
        else        o = __logf(pv) + dlv;
        orow[v] = o;
    }
}

extern "C" void kernel_launch(void* const* d_in, const int* in_sizes, int n_in,
                              void* d_out, int out_size, void* d_ws, size_t ws_size,
                              hipStream_t stream) {
    const float* out_logits = (const float*)d_in[0];
    const float* feature    = (const float*)d_in[1];
    const float* memory_raw = (const float*)d_in[2];
    const int*   content_e  = (const int*)d_in[3];
    const float* Wq = (const float*)d_in[4];
    const float* bq = (const float*)d_in[5];
    const float* Wk = (const float*)d_in[6];
    const float* bk = (const float*)d_in[7];
    const float* sentinel = (const float*)d_in[8];
    float* out = (float*)d_out;

    u16* memb   = (u16*)d_ws;                             // 16384*512 bf16
    u16* featb  = memb   + (size_t)16384 * 512;           // 4096*512
    u16* wqT    = featb  + (size_t)4096 * 512;            // 512*512
    u16* wkE    = wqT    + (size_t)512 * 512;             // 1280*512
    u16* queryb = wkE    + (size_t)NKE * 512;             // 4096*512
    u16* qkb    = queryb + (size_t)4096 * 512;            // 4096*1280
    u16* etb    = qkb    + (size_t)4096 * NKE;            // 16*2048*256 bf16 E^T
    float* rowsum = (float*)(etb + (size_t)BSZ * SRC * TGT); // 4096 f32
    float* lse   = rowsum + 4096;                         // 4096 f32
    int* boff = (int*)(lse + 4096);                       // 16*3008 int
    u16* bucket = (u16*)(boff + 16 * 3008);               // 16*2048 u16

    prep<<<6737, 256, 0, stream>>>(memory_raw, feature, Wq, Wk, sentinel, bk,
                                   out_logits, content_e,
                                   (int4*)memb, (int4*)featb, wqT, wkE,
                                   rowsum, lse, boff, bucket);
    gemm_query<<<dim3(8, 64), 256, 0, stream>>>(featb, wqT, bq, queryb);
    gemm_qk<<<dim3(10, 32), 256, 0, stream>>>(queryb, wkE, qkb);
    gemm_atten<<<512, 256, 0, stream>>>(memb, qkb, content_e, rowsum, etb);
    combine<<<6144, 256, 0, stream>>>(etb, bucket, boff, qkb,
                                      rowsum, lse, out_logits, out);
}

// Round 15
// 93.320 us; speedup vs baseline: 1.3224x; 1.0510x over previous
//
#include <hip/hip_runtime.h>
#include <math.h>

#define BSZ   16
#define LSEQ  1024
#define TGT   256
#define HID   512
#define TV    2000
#define VOC   3000
#define SRC   2048
#define NKE   1280     // WkE rows: 2 j-halves x 640 (512 d + sentinel + bias + pad)
#define JOFF  640
#define SCALE 0.044194173824159216f   // 1/sqrt(512)

typedef unsigned short u16;
typedef __attribute__((ext_vector_type(8))) short bf16x8;
typedef __attribute__((ext_vector_type(4))) float f32x4;

__device__ __forceinline__ u16 f2bf(float x) {
    unsigned u = __float_as_uint(x);
    u += 0x7FFFu + ((u >> 16) & 1u);
    return (u16)(u >> 16);
}
__device__ __forceinline__ float bf2f(u16 x) {
    return __uint_as_float((unsigned)x << 16);
}

static __device__ __forceinline__ float gelu_exact(float x) {
    return 0.5f * x * (1.0f + erff(x * 0.70710678118654752f));
}

// async 16B global -> LDS (wave-uniform LDS base + lane*16)
__device__ __forceinline__ void gload16(const u16* g, u16* l) {
    __builtin_amdgcn_global_load_lds(
        (const __attribute__((address_space(1))) unsigned int*)g,
        (__attribute__((address_space(3))) unsigned int*)l,
        16, 0, 0);
}

__device__ __forceinline__ void cast8_body(const float4* __restrict__ in,
                                           int4* __restrict__ out, int i) {
    float4 x = in[2 * i], y = in[2 * i + 1];
    unsigned p0 = (unsigned)f2bf(x.x) | ((unsigned)f2bf(x.y) << 16);
    unsigned p1 = (unsigned)f2bf(x.z) | ((unsigned)f2bf(x.w) << 16);
    unsigned p2 = (unsigned)f2bf(y.x) | ((unsigned)f2bf(y.y) << 16);
    unsigned p3 = (unsigned)f2bf(y.z) | ((unsigned)f2bf(y.w) << 16);
    out[i] = make_int4(p0, p1, p2, p3);
}

// ---------------- d1: prep_a — featb cast | Wq^T | WkE build | rowsum zero ----------------
// blocks: [0,1024) cast feature | [1024,1280) Wq^T | [1280,1600) WkE | 1600 rowsum=0
__global__ __launch_bounds__(256) void prep_a(
    const float* __restrict__ feature, const float* __restrict__ Wq,
    const float* __restrict__ Wk, const float* __restrict__ sentinel,
    const float* __restrict__ bk,
    int4* __restrict__ featb, u16* __restrict__ wqT, u16* __restrict__ wkE,
    float* __restrict__ rowsum)
{
    __shared__ float t[32][33];
    const int id = blockIdx.x;
    const int tid = threadIdx.x;
    if (id < 1024) {
        cast8_body((const float4*)feature, featb, id * 256 + tid);
    } else if (id < 1280) {
        int id2 = id - 1024;
        int bx = (id2 & 15) * 32, by = (id2 >> 4) * 32;
        const int tx = tid & 31, ty = tid >> 5;
        #pragma unroll
        for (int k = 0; k < 4; ++k)
            t[ty + 8 * k][tx] = Wq[(size_t)(by + ty + 8 * k) * 512 + bx + tx];
        __syncthreads();
        #pragma unroll
        for (int k = 0; k < 4; ++k)
            wqT[(size_t)(bx + ty + 8 * k) * 512 + by + tx] = f2bf(t[tx][ty + 8 * k]);
    } else if (id < 1600) {
        const int rr = (id - 1280) * 4 + (tid >> 6);   // 0..1279
        const int c = (tid & 63) * 8;
        const int j = rr >= JOFF;
        const int dd = rr - j * JOFF;
        u16* dst = wkE + (size_t)rr * HID + c;
        if (dd < 512) {
            const float* src = Wk + (size_t)dd * 1024 + j * 512 + c;
            #pragma unroll
            for (int k = 0; k < 8; ++k) dst[k] = f2bf(src[k]);
        } else if (dd == 512) {
            #pragma unroll
            for (int k = 0; k < 8; ++k) dst[k] = f2bf(sentinel[c + k]);
        } else if (dd == 513) {
            #pragma unroll
            for (int k = 0; k < 8; ++k) dst[k] = f2bf(bk[j * 512 + c + k]);
        } else {
            #pragma unroll
            for (int k = 0; k < 8; ++k) dst[k] = 0;
        }
    } else {
        float4* rz = (float4*)rowsum;
        for (int i = tid; i < 1024; i += 256) rz[i] = make_float4(0.f, 0.f, 0.f, 0.f);
    }
}

// ---------------- d2: query GEMM (512 blocks) + memb cast (4096 blocks) ----------------
__global__ __launch_bounds__(256) void k_query(
    const u16* __restrict__ feat, const u16* __restrict__ wqT,
    const float* __restrict__ bq, u16* __restrict__ queryb,
    const float* __restrict__ memory_raw, int4* __restrict__ memb)
{
    __shared__ u16 sbuf[2 * 2048 * 2];   // As | Bs (16 KB)
    const int id = blockIdx.x;
    const int tid = threadIdx.x;
    if (id >= 512) {
        cast8_body((const float4*)memory_raw, memb, (id - 512) * 256 + tid);
        return;
    }
    u16* As = sbuf;
    u16* Bs = sbuf + 2 * 2048;
    const int lane = tid & 63;
    const int w = tid >> 6;
    const int wr = (w >> 1) * 32, wc = (w & 1) * 32;
    const int m0 = (id >> 3) * 64, n0 = (id & 7) * 64;

    const int srow = tid >> 2, scol = (tid & 3) * 8;
    const u16* gA = feat + (size_t)(m0 + srow) * HID + scol;
    const u16* gB = wqT + (size_t)(n0 + srow) * HID + scol;

    const int la = lane & 15, lb = lane >> 4;
    f32x4 acc[2][2] = {};

    gload16(gA, As + w * 512);
    gload16(gB, Bs + w * 512);

    int cur = 0;
    for (int k0 = 0; k0 < HID; k0 += 32) {
        __syncthreads();   // drains vmcnt(0) + barrier
        const u16* Asb = As + cur * 2048;
        const u16* Bsb = Bs + cur * 2048;
        bf16x8 af[2], bf[2];
        #pragma unroll
        for (int i = 0; i < 2; ++i)
            af[i] = *(const bf16x8*)(Asb + (wr + i * 16 + la) * 32 + lb * 8);
        #pragma unroll
        for (int j = 0; j < 2; ++j)
            bf[j] = *(const bf16x8*)(Bsb + (wc + j * 16 + la) * 32 + lb * 8);
        if (k0 + 32 < HID) {
            const int nb = cur ^ 1;
            gload16(gA + k0 + 32, As + nb * 2048 + w * 512);
            gload16(gB + k0 + 32, Bs + nb * 2048 + w * 512);
        }
        #pragma unroll
        for (int i = 0; i < 2; ++i)
            #pragma unroll
            for (int j = 0; j < 2; ++j)
                acc[i][j] = __builtin_amdgcn_mfma_f32_16x16x32_bf16(af[i], bf[j], acc[i][j], 0, 0, 0);
        cur ^= 1;
    }

    const int r_l = (lane >> 4) * 4, c_l = lane & 15;
    #pragma unroll
    for (int j = 0; j < 2; ++j) {
        const int n = n0 + wc + j * 16 + c_l;
        const float bv = bq[n];
        #pragma unroll
        for (int i = 0; i < 2; ++i)
            #pragma unroll
            for (int r = 0; r < 4; ++r) {
                const int m = m0 + wr + i * 16 + r_l + r;
                queryb[(size_t)m * HID + n] = f2bf(gelu_exact(acc[i][j][r] + bv));
            }
    }
}

// ---------------- MFMA GEMM body (128x128, BK=32) for qk and atten ----------------
template<int EPI, int LDA, int LDB>
__device__ __forceinline__ void gemm_body(
    int m0, int n0, int z,
    const u16* __restrict__ Abase, const u16* __restrict__ Bbase,
    u16* __restrict__ outb,
    const int* __restrict__ ce, float* __restrict__ rowsum,
    u16* __restrict__ As, u16* __restrict__ Bs)   // each 2*4096 u16
{
    const int tid = threadIdx.x;
    const int lane = tid & 63;
    const int w = tid >> 6;
    const int wr = (w >> 1) * 64, wc = (w & 1) * 64;

    const u16* Ag = Abase;
    const u16* Bg = Bbase;
    if (EPI == 2) {
        Ag = Abase + (size_t)(z >> 1) * LSEQ * HID;
        Bg = Bbase + (size_t)(z >> 1) * TGT * NKE + (size_t)(z & 1) * JOFF;
    }

    const int chunkrow = lane >> 2;
    const int colc = (lane & 3) * 8;
    const int c0 = w * 2, c1 = c0 + 1;
    const u16* gA0 = Ag + (size_t)(m0 + c0 * 16 + chunkrow) * LDA + colc;
    const u16* gA1 = Ag + (size_t)(m0 + c1 * 16 + chunkrow) * LDA + colc;
    const u16* gB0 = Bg + (size_t)(n0 + c0 * 16 + chunkrow) * LDB + colc;
    const u16* gB1 = Bg + (size_t)(n0 + c1 * 16 + chunkrow) * LDB + colc;

    const int la = lane & 15, lb = lane >> 4;
    f32x4 acc[4][4] = {};

    gload16(gA0, As + c0 * 512);
    gload16(gA1, As + c1 * 512);
    gload16(gB0, Bs + c0 * 512);
    gload16(gB1, Bs + c1 * 512);

    int cur = 0;
    for (int k0 = 0; k0 < HID; k0 += 32) {
        __syncthreads();
        const u16* Asb = As + cur * 4096;
        const u16* Bsb = Bs + cur * 4096;
        bf16x8 af[4], bfv[4];
        #pragma unroll
        for (int i = 0; i < 4; ++i)
            af[i] = *(const bf16x8*)(Asb + (wr + i * 16 + la) * 32 + lb * 8);
        #pragma unroll
        for (int j = 0; j < 4; ++j)
            bfv[j] = *(const bf16x8*)(Bsb + (wc + j * 16 + la) * 32 + lb * 8);
        if (k0 + 32 < HID) {
            const int nb = cur ^ 1;
            u16* An = As + nb * 4096;
            u16* Bn = Bs + nb * 4096;
            gload16(gA0 + k0 + 32, An + c0 * 512);
            gload16(gA1 + k0 + 32, An + c1 * 512);
            gload16(gB0 + k0 + 32, Bn + c0 * 512);
            gload16(gB1 + k0 + 32, Bn + c1 * 512);
        }
        #pragma unroll
        for (int i = 0; i < 4; ++i)
            #pragma unroll
            for (int j = 0; j < 4; ++j)
                acc[i][j] = __builtin_amdgcn_mfma_f32_16x16x32_bf16(af[i], bfv[j], acc[i][j], 0, 0, 0);
        cur ^= 1;
    }

    const int r_l = (lane >> 4) * 4, c_l = lane & 15;
    if (EPI == 3) {
        #pragma unroll
        for (int j = 0; j < 4; ++j) {
            const int n = n0 + wc + j * 16 + c_l;
            #pragma unroll
            for (int i = 0; i < 4; ++i)
                #pragma unroll
                for (int r = 0; r < 4; ++r) {
                    const int m = m0 + wr + i * 16 + r_l + r;
                    outb[(size_t)m * NKE + n] = f2bf(acc[i][j][r]);
                }
        }
    } else {
        const int b = z >> 1, jj = z & 1;
        float biasc[4];
        #pragma unroll
        for (int j = 0; j < 4; ++j) {
            const int n = n0 + wc + j * 16 + c_l;   // t
            biasc[j] = bf2f(Bbase[(size_t)(b * TGT + n) * NKE + jj * JOFF + 513]);
        }
        const int* ceb = ce + (size_t)b * SRC;
        float csum[4] = {0.f, 0.f, 0.f, 0.f};
        #pragma unroll
        for (int i = 0; i < 4; ++i)
            #pragma unroll
            for (int r = 0; r < 4; ++r) {
                const int m = m0 + wr + i * 16 + r_l + r;      // l
                const int cm = ceb[2 * m + jj];
                const size_t rowbase = ((size_t)b * SRC + jj * 1024 + m) * TGT;
                #pragma unroll
                for (int j = 0; j < 4; ++j) {
                    float ev = (cm == 0) ? 0.f
                             : __expf((acc[i][j][r] + biasc[j]) * SCALE);
                    outb[rowbase + n0 + wc + j * 16 + c_l] = f2bf(ev);
                    csum[j] += ev;
                }
            }
        #pragma unroll
        for (int j = 0; j < 4; ++j) {
            csum[j] += __shfl_xor(csum[j], 16, 64);
            csum[j] += __shfl_xor(csum[j], 32, 64);
        }
        const int jsel = lane >> 4;
        float myv = (jsel == 0) ? csum[0] : (jsel == 1) ? csum[1]
                  : (jsel == 2) ? csum[2] : csum[3];
        atomicAdd(&rowsum[b * TGT + n0 + wc + jsel * 16 + c_l], myv);
    }
}

// ---------------- d3: qk GEMM (320) + logits LSE (1024) + bucket build (16) ----------------
__global__ __launch_bounds__(256) void k_qk(
    const u16* __restrict__ queryb, const u16* __restrict__ wkE,
    u16* __restrict__ qkb,
    const float* __restrict__ logits, float* __restrict__ lse,
    const int* __restrict__ ce, int* __restrict__ boff, u16* __restrict__ bucket)
{
    __shared__ u16 sbuf[4 * 4096];   // 32 KB: GEMM As|Bs, or bucket cnt|part overlay
    const int id = blockIdx.x;
    const int tid = threadIdx.x;
    if (id < 320) {
        gemm_body<3, 512, 512>((id / 10) * 128, (id % 10) * 128, 0,
                               queryb, wkE, qkb, nullptr, nullptr,
                               sbuf, sbuf + 2 * 4096);
    } else if (id < 1344) {
        // logits LSE: 4 rows per block, one wave per row (TV = 500 float4)
        const int row = (id - 320) * 4 + (tid >> 6);
        const int lane = tid & 63;
        const float4* lrow4 = (const float4*)(logits + (size_t)row * TV);
        float4 v4[8];
        float m = -INFINITY;
        #pragma unroll
        for (int k = 0; k < 8; ++k) {
            int idx = lane + 64 * k;
            if (idx < 500) {
                v4[k] = lrow4[idx];
                m = fmaxf(m, fmaxf(fmaxf(v4[k].x, v4[k].y), fmaxf(v4[k].z, v4[k].w)));
            } else {
                v4[k] = make_float4(-INFINITY, -INFINITY, -INFINITY, -INFINITY);
            }
        }
        #pragma unroll
        for (int o = 32; o > 0; o >>= 1) m = fmaxf(m, __shfl_xor(m, o, 64));
        float s = 0.f;
        #pragma unroll
        for (int k = 0; k < 8; ++k)
            s += __expf(v4[k].x - m) + __expf(v4[k].y - m)
               + __expf(v4[k].z - m) + __expf(v4[k].w - m);
        #pragma unroll
        for (int o = 32; o > 0; o >>= 1) s += __shfl_xor(s, o, 64);
        if (lane == 0) lse[row] = m + __logf(s);
    } else {
        // bucket build: one block per batch (LDS overlaid on sbuf)
        const int b = id - 1344;
        int* cnt = (int*)sbuf;          // 3000 ints
        int* part = cnt + VOC;          // 256 ints (13 KB total < 32 KB)
        const int* ceb = ce + (size_t)b * SRC;
        for (int v = tid; v < VOC; v += 256) cnt[v] = 0;
        __syncthreads();
        for (int s = tid; s < SRC; s += 256) atomicAdd(&cnt[ceb[s]], 1);
        __syncthreads();
        const int base = tid * 12;
        int lc[12];
        int tot = 0;
        #pragma unroll
        for (int k = 0; k < 12; ++k) {
            int v = base + k;
            lc[k] = (v < VOC) ? cnt[v] : 0;
            tot += lc[k];
        }
        part[tid] = tot;
        __syncthreads();
        for (int d = 1; d < 256; d <<= 1) {
            int val = (tid >= d) ? part[tid - d] : 0;
            __syncthreads();
            part[tid] += val;
            __syncthreads();
        }
        int run = part[tid] - tot;
        int* boffb = boff + b * 3008;
        #pragma unroll
        for (int k = 0; k < 12; ++k) {
            int v = base + k;
            if (v < VOC) { boffb[v] = run; cnt[v] = run; run += lc[k]; }
        }
        if (tid == 0) boffb[VOC] = SRC;
        __syncthreads();
        for (int s = tid; s < SRC; s += 256) {
            int idv = ceb[s];
            int jl = (s & 1) * 1024 + (s >> 1);
            int pos = atomicAdd(&cnt[idv], 1);
            bucket[(size_t)b * SRC + pos] = (u16)jl;
        }
    }
}

// ---------------- d4: atten — 512 blocks, XCD-grouped per (b,jj) ----------------
__global__ __launch_bounds__(256) void gemm_atten(
    const u16* __restrict__ memb, const u16* __restrict__ qkb,
    const int* __restrict__ ce, float* __restrict__ rowsum,
    u16* __restrict__ etb)
{
    __shared__ u16 As[2 * 4096];
    __shared__ u16 Bs[2 * 4096];
    const int i = blockIdx.x;
    const int xcd = i & 7, slot = i >> 3;        // slot in [0,64)
    const int bjj = xcd + 8 * (slot >> 4);       // [0,32) = b*2+jj
    const int inner = slot & 15;                 // 8 l-tiles x 2 t-tiles
    gemm_body<2, 512, NKE>((inner >> 1) * 128, (inner & 1) * 128, bjj,
                           memb, qkb, etb, ce, rowsum, As, Bs);
}

// ---------------- d5: combine — one 256-v chunk per block, LDS-staged bucket slice ----------------
__global__ __launch_bounds__(256) void combine(
    const u16* __restrict__ etb, const u16* __restrict__ bucket,
    const int* __restrict__ boff, const u16* __restrict__ qkb,
    const float* __restrict__ rowsum, const float* __restrict__ lse,
    const float* __restrict__ out_logits, float* __restrict__ out)
{
    __shared__ float acc[8][256];
    __shared__ u16 sbuck[SRC];
    __shared__ float rcInv[8], rcGZ[8], rcEdl[8], rcDl[8];
    const int i = blockIdx.x;
    const int xcd = i & 7, slot = i >> 3;      // slot in [0,768)
    const int b = xcd + 8 * (slot / 384);      // all 384 blocks of b on one XCD
    const int inner = slot % 384;
    const int tc = inner / 12, vs = inner % 12;
    const int t0 = tc * 8;
    const int vbase = vs * 256;
    const int tid = threadIdx.x;
    const float EPSF = 1.1920929e-07f;

    if (tid < 8) {
        const int bt = b * TGT + t0 + tid;
        const float sent_v = bf2f(qkb[(size_t)bt * NKE + 512]) * SCALE;
        const float se = __expf(sent_v);
        const float sm = rowsum[bt] + se;
        const float inv = 1.0f / sm;
        const float g = sent_v - __logf(sm);
        const float eg = se * inv;
        const float dl = __logf(1.0f - eg + EPSF) - log1pf(-eg + EPSF);
        rcInv[tid] = inv;
        rcGZ[tid] = g - lse[bt];
        rcEdl[tid] = __expf(dl);
        rcDl[tid] = dl;
    }

    const int* boffb = boff + b * 3008;
    const u16* bukb = bucket + (size_t)b * SRC;
    const u16* etbb = etb + (size_t)b * SRC * TGT;

    const int vend = (vbase + 256 < VOC) ? vbase + 256 : VOC;
    const int e_lo = boffb[vbase];
    const int e_hi = boffb[vend];
    for (int e = e_lo + tid; e < e_hi; e += 256) sbuck[e - e_lo] = bukb[e];
    __syncthreads();

    {
        float a[8] = {0.f, 0.f, 0.f, 0.f, 0.f, 0.f, 0.f, 0.f};
        const int v = vbase + tid;
        if (v < VOC) {
            const int i0 = boffb[v] - e_lo;
            const int i1 = boffb[v + 1] - e_lo;
            for (int e = i0; e < i1; ++e) {
                const int s = sbuck[e];
                int4 u = *(const int4*)(etbb + (size_t)s * TGT + t0);
                a[0] += bf2f((u16)(u.x & 0xffff));
                a[1] += bf2f((u16)((unsigned)u.x >> 16));
                a[2] += bf2f((u16)(u.y & 0xffff));
                a[3] += bf2f((u16)((unsigned)u.y >> 16));
                a[4] += bf2f((u16)(u.z & 0xffff));
                a[5] += bf2f((u16)((unsigned)u.z >> 16));
                a[6] += bf2f((u16)(u.w & 0xffff));
                a[7] += bf2f((u16)((unsigned)u.w >> 16));
            }
        }
        #pragma unroll
        for (int k = 0; k < 8; ++k) acc[k][tid] = a[k];
    }
    __syncthreads();

    const int r = tid >> 5;
    const int vl0 = tid & 31;
    const int bt = b * TGT + t0 + r;
    const float inv = rcInv[r], gZ = rcGZ[r], edl = rcEdl[r], dlv = rcDl[r];
    const float* lrow = out_logits + (size_t)bt * TV;
    float* orow = out + (size_t)bt * VOC;
    #pragma unroll
    for (int kk = 0; kk < 8; ++kk) {
        const int vloc = vl0 + 32 * kk;
        const int v = vbase + vloc;
        if (v >= VOC) continue;
        float pv = acc[r][vloc] * inv + EPSF;
        float o;
        if (v < TV) o = __logf(__expf(lrow[v] + gZ) + pv * edl);
        else        o = __logf(pv) + dlv;
        orow[v] = o;
    }
}

extern "C" void kernel_launch(void* const* d_in, const int* in_sizes, int n_in,
                              void* d_out, int out_size, void* d_ws, size_t ws_size,
                              hipStream_t stream) {
    const float* out_logits = (const float*)d_in[0];
    const float* feature    = (const float*)d_in[1];
    const float* memory_raw = (const float*)d_in[2];
    const int*   content_e  = (const int*)d_in[3];
    const float* Wq = (const float*)d_in[4];
    const float* bq = (const float*)d_in[5];
    const float* Wk = (const float*)d_in[6];
    const float* bk = (const float*)d_in[7];
    const float* sentinel = (const float*)d_in[8];
    float* out = (float*)d_out;

    u16* memb   = (u16*)d_ws;                             // 16384*512 bf16
    u16* featb  = memb   + (size_t)16384 * 512;           // 4096*512
    u16* wqT    = featb  + (size_t)4096 * 512;            // 512*512
    u16* wkE    = wqT    + (size_t)512 * 512;             // 1280*512
    u16* queryb = wkE    + (size_t)NKE * 512;             // 4096*512
    u16* qkb    = queryb + (size_t)4096 * 512;            // 4096*1280
    u16* etb    = qkb    + (size_t)4096 * NKE;            // 16*2048*256 bf16 E^T
    float* rowsum = (float*)(etb + (size_t)BSZ * SRC * TGT); // 4096 f32
    float* lse   = rowsum + 4096;                         // 4096 f32
    int* boff = (int*)(lse + 4096);                       // 16*3008 int
    u16* bucket = (u16*)(boff + 16 * 3008);               // 16*2048 u16

    prep_a<<<1601, 256, 0, stream>>>(feature, Wq, Wk, sentinel, bk,
                                     (int4*)featb, wqT, wkE, rowsum);
    k_query<<<4608, 256, 0, stream>>>(featb, wqT, bq, queryb, memory_raw, (int4*)memb);
    k_qk<<<1360, 256, 0, stream>>>(queryb, wkE, qkb, out_logits, lse,
                                   content_e, boff, bucket);
    gemm_atten<<<512, 256, 0, stream>>>(memb, qkb, content_e, rowsum, etb);
    combine<<<6144, 256, 0, stream>>>(etb, bucket, boff, qkb,
                                      rowsum, lse, out_logits, out);
}